// Round 10
// baseline (463.392 us; speedup 1.0000x reference)
//
#include <hip/hip_runtime.h>
#include <math.h>

// Problem constants
#define T_LEN 512
#define B_SZ  32
#define NHEAD 8
#define DHEAD 64
#define H_DIM 512
#define TBTOK 16384          // T*B
#define P_DIM 1152
#define P_PAD 1280           // P padded for the 320-wide gemm

typedef unsigned short ushort_t;
typedef short short8 __attribute__((ext_vector_type(8)));
typedef float f32x4 __attribute__((ext_vector_type(4)));

__device__ __forceinline__ ushort_t f2bf(float f) {
    union { float f; unsigned int u; } v; v.f = f;
    unsigned int r = v.u + 0x7fffu + ((v.u >> 16) & 1u);
    return (ushort_t)(r >> 16);
}
__device__ __forceinline__ float bf2f(ushort_t h) {
    union { unsigned int u; float f; } v; v.u = ((unsigned int)h) << 16;
    return v.f;
}
__device__ __forceinline__ void gload_lds16(const void* g, void* l) {
    __builtin_amdgcn_global_load_lds(
        (const __attribute__((address_space(1))) void*)g,
        (__attribute__((address_space(3))) void*)l, 16, 0, 0);
}

// ---------------------------------------------------------------------------
// Weight fp32 -> bf16 packing (first 6 matrices, flat) + accum zero
// ---------------------------------------------------------------------------
__global__ __launch_bounds__(256) void convert_weights(
    const float* __restrict__ wq, const float* __restrict__ wk,
    const float* __restrict__ wv, const float* __restrict__ wo,
    const float* __restrict__ w1, const float* __restrict__ w2,
    ushort_t* __restrict__ dst, float* __restrict__ accum)
{
    if (blockIdx.x == 0 && threadIdx.x < 2) accum[threadIdx.x] = 0.f;
    const unsigned int offs[7] = {0u, 327680u, 655360u, 1245184u, 1507328u,
                                  1769472u, 2031616u};
    unsigned int c = (blockIdx.x * 256 + threadIdx.x) * 4;   // element offset
    const float* srcs[6] = {wq, wk, wv, wo, w1, w2};
    int s = 0;
#pragma unroll
    for (int i = 0; i < 5; i++) s += (c >= offs[i + 1]) ? 1 : 0;
    float4 v = *(const float4*)(srcs[s] + (c - offs[s]));
    ushort4 o;
    o.x = f2bf(v.x); o.y = f2bf(v.y); o.z = f2bf(v.z); o.w = f2bf(v.w);
    *(ushort4*)(dst + c) = o;
}

// ---------------------------------------------------------------------------
// L1W -> [1280][1152] bf16 (zero pad rows), L2W -> [1280][1280] bf16
// (zero pad rows+cols), plus padded L1b/L2b/OW float vectors (1280).
// ---------------------------------------------------------------------------
__global__ __launch_bounds__(256) void pad_weights(
    const float* __restrict__ l1, const float* __restrict__ l2,
    const float* __restrict__ L1b, const float* __restrict__ L2b,
    const float* __restrict__ OW,
    ushort_t* __restrict__ l1d, ushort_t* __restrict__ l2d,
    float* __restrict__ L1bp, float* __restrict__ L2bp, float* __restrict__ OWp)
{
    int blk = blockIdx.x;
    if (blk < 1440) {                       // l1: 1280*1152 = 1,474,560 elems
        int o4 = (blk * 256 + threadIdx.x) * 4;
        int row = o4 / 1152;
        int col = o4 - row * 1152;
        ushort4 o; o.x = 0; o.y = 0; o.z = 0; o.w = 0;
        if (row < 1152) {
            float4 v = *(const float4*)(l1 + (size_t)row * 1152 + col);
            o.x = f2bf(v.x); o.y = f2bf(v.y); o.z = f2bf(v.z); o.w = f2bf(v.w);
        }
        *(ushort4*)(l1d + o4) = o;
    } else if (blk < 3040) {                // l2: 1280*1280 = 1,638,400 elems
        int o4 = ((blk - 1440) * 256 + threadIdx.x) * 4;
        int row = o4 / 1280;
        int col = o4 - row * 1280;
        ushort4 o; o.x = 0; o.y = 0; o.z = 0; o.w = 0;
        if (row < 1152 && col < 1152) {     // 4-chunk never straddles 1152 (4|1152)
            float4 v = *(const float4*)(l2 + (size_t)row * 1152 + col);
            o.x = f2bf(v.x); o.y = f2bf(v.y); o.z = f2bf(v.z); o.w = f2bf(v.w);
        }
        *(ushort4*)(l2d + o4) = o;
    } else {
        for (int i = threadIdx.x; i < P_PAD; i += 256) {
            L1bp[i] = (i < P_DIM) ? L1b[i] : 0.f;
            L2bp[i] = (i < P_DIM) ? L2b[i] : 0.f;
            OWp[i]  = (i < P_DIM) ? OW[i]  : 0.f;
        }
    }
}

// ---------------------------------------------------------------------------
// Embedding / gather (bf16 outputs) + fused logits tail dot
// ---------------------------------------------------------------------------
__global__ __launch_bounds__(256) void embed_kernel(
    const int* __restrict__ ans, const int* __restrict__ cans,
    const int* __restrict__ labels, const float* __restrict__ mask,
    const int* __restrict__ qids, const int* __restrict__ sids,
    const float* __restrict__ smask,
    const float* __restrict__ Eq, const float* __restrict__ Es,
    const float* __restrict__ Ea, const float* __restrict__ El,
    ushort_t* __restrict__ pred_bf, ushort_t* __restrict__ value_bf,
    const float* __restrict__ OW, const float* __restrict__ Ob,
    float* __restrict__ lgits)
{
    __shared__ float red[4];
    int m = blockIdx.x;              // token = t*B + b
    int tid = threadIdx.x;           // 256
    float mval = mask[m];
    int qid = qids[m];
    int a   = ans[m] - 1;
    int ca  = cans[m] - 1;
    int lb  = labels[m];
    ushort_t* pr = pred_bf  + (size_t)m * P_DIM;
    ushort_t* vr = value_bf + (size_t)m * P_DIM;

    float part = 0.f;
    if (tid < 128) {
        ushort_t qv = f2bf(Eq[(size_t)qid * 128 + tid]);
        pr[512 + tid] = qv;
        vr[768 + tid] = qv;
        part = bf2f(qv) * OW[512 + tid];
    }
    int d = tid;                     // 0..255
    float s = 0.f;
#pragma unroll
    for (int j = 0; j < 8; j++) {
        int  sid = sids[m * 8 + j];
        float sm = smask[m * 8 + j];
        s += Es[(size_t)sid * 256 + d] * sm;
    }
    ushort_t sb = f2bf(s);
    pr[640 + d] = sb;
    vr[896 + d] = sb;
    ushort_t cab = f2bf(Ea[ca * 256 + d]);
    pr[896 + d] = cab;
    vr[512 + d] = cab;
    vr[256 + d] = f2bf(Ea[a * 256 + d] * mval);
    vr[0   + d] = f2bf(El[lb * 256 + d] * mval);

    part = fmaf(bf2f(sb),  OW[640 + d], part);
    part = fmaf(bf2f(cab), OW[896 + d], part);
#pragma unroll
    for (int off = 32; off >= 1; off >>= 1) part += __shfl_xor(part, off, 64);
    if ((tid & 63) == 0) red[tid >> 6] = part;
    __syncthreads();
    if (tid == 0) lgits[m] = red[0] + red[1] + red[2] + red[3] + Ob[0];
}

// ---------------------------------------------------------------------------
// TLP-overlapped MFMA GEMM (r19 = r18 structure + r11-verified LDS layout).
// 128 x (64*JC) tile, BK=64, 512 thr = 8 waves (2M x 4N), per-wave C =
// 64 x (16*JC) (acc[4][JC]). Grid = 128 x 4 = 512 wgs = 2+ blocks/CU
// (m114 TLP: the other block's MFMA hides this block's stage-wait and
// read-burst -- r18 proved it: occupancy 18->38%, held ~51us even with
// 4-way LDS conflicts).
// r18 post-mortem: 64-ushort rows make the bank index row-independent
// (128B row stride = full 32-bank wrap) -> same-chunk lanes pile on the
// same 4 banks: 5.9M conflicts/dispatch measured. Fix: store each K-tile
// as TWO khalf regions of [rows][32] (r11's layout, measured 0-conflict
// with these exact read shapes): A 2x128x32 (16KB), B 2xBNx32 (8*JC KB);
// DMA roll (row>>1)&3 on source chunk, frag read csw=((quad+((fr>>1)&3))
// &3)*8. Same total LDS, same occupancy. Serial loop: stage both khalves
// -> vmcnt(0) -> barrier -> compute kh0,kh1 -> barrier.
// MODE 1: bias + optional relu, bf16 row-major store (ldc)
// MODE 3: bias + relu, dot with OW, atomicAdd into lg[row] (no store)
// MODE 4: JC=2, V^T scatter [bh][d][t]; A rows consumed (b,t)-permuted
//         (affine within a 128-row tile)
// MODE 5: JC=4, merged Q|K scatter [bh][t][d]
// Epilogue stages alias SH (all waves past final barrier; wave-private).
// ---------------------------------------------------------------------------
template<int JC, int MODE, bool RELU>
__global__ __launch_bounds__(512, 4) void gemmT(
    const ushort_t* __restrict__ A, int lda,
    const ushort_t* __restrict__ W, int ldw,
    const float* __restrict__ bias, const float* __restrict__ bias2,
    ushort_t* __restrict__ Cb, ushort_t* __restrict__ Cb2, int ldc, int K,
    const float* __restrict__ OW, float* __restrict__ lg)
{
    constexpr int BN = JC * 64;
    // [A kh0][A kh1][B kh0][B kh1], rows of 32 ushorts
    __shared__ __align__(16) ushort_t SH[2 * 128 * 32 + 2 * BN * 32];
    ushort_t* Bs0 = SH + 2 * 128 * 32;

    const int m0 = blockIdx.x * 128;
    const int n0 = blockIdx.y * BN;
    const int wave = threadIdx.x >> 6;
    const int lane = threadIdx.x & 63;
    const int wm = wave >> 2, wn = wave & 3;   // 2M x 4N waves
    const int fr   = lane & 15;
    const int quad = lane >> 4;
    // frag read roll (r11-verified): row mod 16 == fr -> (row>>1)&3 ==
    // (fr>>1)&3 (row bases wm*64,i*16,wn*JC*16,j*16 all mult of 8 elems)
    const int csw  = ((quad + ((fr >> 1) & 3)) & 3) * 8;

    // staging: instr covers 16 rows of 32 ushorts; lane -> row +(lane>>2),
    // phys chunk lane&3, source chunk ((lane&3)-((slr>>1)&3))&3 (row-block
    // bases are mult of 16 -> drop out of the roll).
    const int slr = lane >> 2;
    const int sc  = (((lane & 3) - ((slr >> 1) & 3)) & 3) * 8;
    const ushort_t* Asrc;
    size_t aRS;   // A address stride per +1 staged row
    if (MODE == 4) {
        // token(r) = ((m0&511)+r)*32 + (m0>>9); affine in r (128 | m0)
        Asrc = A + (size_t)(((m0 & 511) + slr) * 32 + (m0 >> 9)) * lda + sc;
        aRS  = (size_t)32 * lda;
    } else {
        Asrc = A + (size_t)(m0 + slr) * lda + sc;
        aRS  = (size_t)lda;
    }
    const ushort_t* Wsrc = W + (size_t)(n0 + slr) * ldw + sc;
    const int NT = K >> 6;

    auto stA = [&](int t, int kh) {      // 8 instrs: 1 per wave (128 rows)
        int rb = wave * 16;
        gload_lds16(Asrc + (size_t)rb * aRS + (t * 64 + kh * 32),
                    &SH[(kh * 128 + rb) * 32]);
    };
    auto stB = [&](int t, int kh) {      // 4*JC instrs (BN rows)
#pragma unroll
        for (int n = 0; n < JC / 2; n++) {
            int rb = (wave + 8 * n) * 16;
            gload_lds16(Wsrc + (size_t)rb * ldw + (t * 64 + kh * 32),
                        &Bs0[(kh * BN + rb) * 32]);
        }
        if (JC & 1) {
            if (wave < 4) {
                int rb = (wave + 8 * (JC / 2)) * 16;
                gload_lds16(Wsrc + (size_t)rb * ldw + (t * 64 + kh * 32),
                            &Bs0[(kh * BN + rb) * 32]);
            }
        }
    };

    f32x4 acc[4][JC] = {};

    for (int t = 0; t < NT; ++t) {
        stA(t, 0); stA(t, 1); stB(t, 0); stB(t, 1);
        asm volatile("s_waitcnt vmcnt(0)" ::: "memory");
        __builtin_amdgcn_s_barrier();
#pragma unroll
        for (int kh = 0; kh < 2; kh++) {
            const ushort_t* Ar = &SH[(kh * 128) * 32];
            const ushort_t* Br = &Bs0[(kh * BN) * 32];
            short8 af[4], bf[JC];
#pragma unroll
            for (int i = 0; i < 4; i++)
                af[i] = *(const short8*)&Ar[(wm * 64 + i * 16 + fr) * 32 + csw];
#pragma unroll
            for (int j = 0; j < JC; j++)
                bf[j] = *(const short8*)&Br[(wn * (JC * 16) + j * 16 + fr) * 32 + csw];
#pragma unroll
            for (int i = 0; i < 4; i++)
#pragma unroll
                for (int j = 0; j < JC; j++)
                    acc[i][j] = __builtin_amdgcn_mfma_f32_16x16x32_bf16(
                        af[i], bf[j], acc[i][j], 0, 0, 0);
        }
        __builtin_amdgcn_s_barrier();    // all reads done before next stage
    }

    // C/D layout per frag: col = fr, row = quad*4 + reg.
    // acc[ii][j] -> row = m0 + wm*64 + ii*16 + quad*4 + r
    const int nbase = n0 + wn * (JC * 16);

    if (MODE == 3) {
#pragma unroll
        for (int ii = 0; ii < 4; ii++)
#pragma unroll
            for (int r = 0; r < 4; r++) {
                int row = m0 + wm * 64 + ii * 16 + quad * 4 + r;
                float part = 0.f;
#pragma unroll
                for (int j = 0; j < JC; j++) {
                    int col = nbase + j * 16 + fr;
                    float v = fmaxf(acc[ii][j][r] + bias[col], 0.f);
                    part = fmaf(v, OW[col], part);
                }
                part += __shfl_xor(part, 1, 64);
                part += __shfl_xor(part, 2, 64);
                part += __shfl_xor(part, 4, 64);
                part += __shfl_xor(part, 8, 64);
                if (fr == 0) atomicAdd(&lg[row], part);
            }
        return;
    }

    if (MODE == 5) {
        // JC=4: per-wave 64 rows x 64 cols = one head's d-range.
        bool side = (nbase >= 512);
        const float* bp = side ? bias2 : bias;
        const int boff  = nbase & 511;
        const float scl = side ? 1.f : 0.125f;
        ushort_t* base  = side ? Cb2 : Cb;
        const int h = (nbase >> 6) & 7;
        ushort_t* etw = SH + wave * (16 * 72);
#pragma unroll
        for (int ii = 0; ii < 4; ii++) {
#pragma unroll
            for (int r = 0; r < 4; r++)
#pragma unroll
                for (int j = 0; j < 4; j++) {
                    float v = (acc[ii][j][r] + bp[boff + j * 16 + fr]) * scl;
                    etw[(quad * 4 + r) * 72 + j * 16 + fr] = f2bf(v);
                }
            int rowb = m0 + wm * 64 + ii * 16;
#pragma unroll
            for (int u = lane; u < 128; u += 64) {
                int rr = u >> 3, cc = (u & 7) * 8;
                int row = rowb + rr;            // token m = t*32 + b
                int tq = row >> 5, b = row & 31;
                short8 val = *(const short8*)&etw[rr * 72 + cc];
                *(short8*)&base[(((size_t)(b * 8 + h)) << 15) + ((size_t)tq << 6) + cc] = val;
            }
        }
        return;
    }

    if (MODE == 4) {
        // JC=2: per-wave 64 rows(m=b*512+t, same b) x 32 cols(d).
        // Transposed stage per 32-t half: 32 d x 32 t, scatter to
        // vtb[bh][d][512].
        ushort_t* etw = SH + wave * (32 * 40);
        const int h = nbase >> 6;
        const int dbase = nbase & 63;
        const int mbase = m0 + wm * 64;
        const int b = mbase >> 9;
        size_t obase0 = (((size_t)(b * 8 + h)) << 15) + ((size_t)dbase << 9)
                        + (mbase & 511);
#pragma unroll
        for (int p = 0; p < 2; p++) {
#pragma unroll
            for (int iiL = 0; iiL < 2; iiL++) {
                int ii = p * 2 + iiL;
#pragma unroll
                for (int r = 0; r < 4; r++) {
                    int rl = iiL * 16 + quad * 4 + r;    // t-offset 0..31
#pragma unroll
                    for (int j = 0; j < 2; j++) {
                        int cl = j * 16 + fr;            // d-offset 0..31
                        float v = acc[ii][j][r] + bias[nbase + cl];
                        etw[cl * 40 + rl] = f2bf(v);
                    }
                }
            }
            size_t obase = obase0 + p * 32;
#pragma unroll
            for (int u = lane; u < 128; u += 64) {
                int dr = u >> 2, cc = (u & 3) * 8;
                short8 val = *(const short8*)&etw[dr * 40 + cc];
                *(short8*)&Cb[obase + ((size_t)dr << 9) + cc] = val;
            }
        }
        return;
    }

    // MODE 1: per-ii stage 16 rows x JC*16 cols in wave-private LDS slice
    // (aliased onto SH), then coalesced short8 stores.
    {
        constexpr int STR = JC * 16 + 8;
        constexpr int CPR = 2 * JC;            // short8 chunks per row
        ushort_t* etw = SH + wave * (16 * STR);
#pragma unroll
        for (int ii = 0; ii < 4; ii++) {
#pragma unroll
            for (int r = 0; r < 4; r++)
#pragma unroll
                for (int j = 0; j < JC; j++) {
                    float v = acc[ii][j][r] + bias[nbase + j * 16 + fr];
                    if (RELU) v = fmaxf(v, 0.f);
                    etw[(quad * 4 + r) * STR + j * 16 + fr] = f2bf(v);
                }
            int rowb = m0 + wm * 64 + ii * 16;
#pragma unroll
            for (int u = lane; u < 16 * CPR; u += 64) {
                int rr = u / CPR;
                int cc = u - rr * CPR;
                short8 val = *(const short8*)&etw[rr * STR + cc * 8];
                *(short8*)&Cb[(size_t)(rowb + rr) * ldc + nbase + cc * 8] = val;
            }
        }
    }
}

// ---------------------------------------------------------------------------
// MFMA flash attention, no-rescale softmax, cooperative async K/V LDS staging
// ---------------------------------------------------------------------------
__global__ __launch_bounds__(256) void attn_mfma(
    const ushort_t* __restrict__ qb, const ushort_t* __restrict__ kb,
    const ushort_t* __restrict__ vtb, const float* __restrict__ mask,
    const float* __restrict__ gammas, ushort_t* __restrict__ attnc)
{
    __shared__ __align__(16) ushort_t kbuf[2][64 * 64];  // 16 KB
    __shared__ __align__(16) ushort_t vbuf[2][64 * 64];  // 16 KB
    __shared__ __align__(16) ushort_t ps[4][16][72];     // P / O stage, per wave
    __shared__ float decayF[512];
    __shared__ float mneg[512];

    const int bh  = blockIdx.x;          // b*8 + h
    const int b   = bh >> 3;
    const int h   = bh & 7;
    const int qt0 = (7 - blockIdx.y) * 64;   // heavy tiles first
    const int tid  = threadIdx.x;
    const int wave = tid >> 6;
    const int lane = tid & 63;
    const int fr   = lane & 15;
    const int quad = lane >> 4;

    {   // LUTs: decay' = clip(exp(-sp*sqrt(d)),1e-5,..)*log2e ; mneg = 0/-1e32
        float g  = gammas[h];
        float sp = (g > 20.f) ? g : log1pf(expf(g));
        for (int i = tid; i < 512; i += 256) {
            decayF[i] = fmaxf(exp2f(-sp * 1.44269504f * sqrtf((float)i)), 1e-5f)
                        * 1.44269504f;
            mneg[i]   = (mask[(size_t)i * B_SZ + b] == 0.f) ? -1e32f : 0.f;
        }
    }

    const int qr0 = qt0 + wave * 16;
    const ushort_t* qbase = qb  + ((size_t)bh << 15);   // [t][64]
    const ushort_t* kbase = kb  + ((size_t)bh << 15);
    const ushort_t* vbase = vtb + ((size_t)bh << 15);   // [d][512]

    short8 af0 = *(const short8*)(qbase + (size_t)(qr0 + fr) * 64 + quad * 8);
    short8 af1 = *(const short8*)(qbase + (size_t)(qr0 + fr) * 64 + 32 + quad * 8);
    const short8 ones = {0x3F80, 0x3F80, 0x3F80, 0x3F80,
                         0x3F80, 0x3F80, 0x3F80, 0x3F80};

    const int rl0 = wave * 16 + (lane >> 3);
    const int rl1 = rl0 + 8;
    const int sc0 = (((lane & 7) - rl0) & 7) * 8;   // ushort offset
    const int sc1 = (((lane & 7) - rl1) & 7) * 8;

    auto stage = [&](int kt, int bufi) {
        gload_lds16(kbase + (size_t)(kt + rl0) * 64 + sc0, &kbuf[bufi][(wave * 16) * 64]);
        gload_lds16(kbase + (size_t)(kt + rl1) * 64 + sc1, &kbuf[bufi][(wave * 16 + 8) * 64]);
        gload_lds16(vbase + (size_t)rl0 * T_LEN + kt + sc0, &vbuf[bufi][(wave * 16) * 64]);
        gload_lds16(vbase + (size_t)rl1 * T_LEN + kt + sc1, &vbuf[bufi][(wave * 16 + 8) * 64]);
    };
    auto frag = [&](const ushort_t* buf, int row, int lchunk) -> short8 {
        return *(const short8*)&buf[row * 64 + ((lchunk + row) & 7) * 8];
    };

    stage(0, 0);

    f32x4 o[4] = {};                    // O[q=quad*4+r][d=j2*16+fr]
    f32x4 lacc = {};                    // row sums, same layout rows
    int bufi = 0;

    for (int kt0 = 0; kt0 <= qt0; kt0 += 64) {
        __syncthreads();                // drains staged loads; buffer handoff
        if (kt0 < qt0) stage(kt0 + 64, bufi ^ 1);   // prefetch during compute
        const bool diag = (kt0 == qt0);
        const ushort_t* kb_ = kbuf[bufi];
        const ushort_t* vb_ = vbuf[bufi];

        // ---- S = Q K^T (16 x 64) ----
        f32x4 sacc[4] = {};
#pragma unroll
        for (int j = 0; j < 4; j++) {
            int row = j * 16 + fr;
            short8 k0 = frag(kb_, row, quad);
            short8 k1 = frag(kb_, row, quad + 4);
            sacc[j] = __builtin_amdgcn_mfma_f32_16x16x32_bf16(af0, k0, sacc[j], 0, 0, 0);
            sacc[j] = __builtin_amdgcn_mfma_f32_16x16x32_bf16(af1, k1, sacc[j], 0, 0, 0);
        }

        // ---- softmax (no rescale): p = exp2(fma(s, decay', mneg)) ----
#pragma unroll
        for (int j = 0; j < 4; j++) {
            int kg = kt0 + j * 16 + fr;
            float mn = mneg[kg];
            int qgb = qr0 + quad * 4;
            if (!diag) {
                int base = qgb - kg;
#pragma unroll
                for (int r = 0; r < 4; r++) {
                    float t = fmaf(sacc[j][r], decayF[base + r], mn);
                    union { float f; unsigned u; } cv; cv.f = exp2f(t);
                    ps[wave][quad * 4 + r][j * 16 + fr] = (ushort_t)(cv.u >> 16);
                }
            } else {
#pragma unroll
                for (int r = 0; r < 4; r++) {
                    int didx = qgb + r - kg;
                    float dec = decayF[didx > 0 ? didx : 0];
                    float t = fmaf(sacc[j][r], dec, mn);
                    if (didx <= 0) t = -1e32f;      // causal (kg >= qg)
                    union { float f; unsigned u; } cv; cv.f = exp2f(t);
                    ps[wave][quad * 4 + r][j * 16 + fr] = (ushort_t)(cv.u >> 16);
                }
            }
        }
        short8 pf0 = *(const short8*)&ps[wave][fr][quad * 8];
        short8 pf1 = *(const short8*)&ps[wave][fr][32 + quad * 8];
        lacc = __builtin_amdgcn_mfma_f32_16x16x32_bf16(pf0, ones, lacc, 0, 0, 0);
        lacc = __builtin_amdgcn_mfma_f32_16x16x32_bf16(pf1, ones, lacc, 0, 0, 0);
#pragma unroll
        for (int j2 = 0; j2 < 4; j2++) {
            int row = j2 * 16 + fr;
            short8 v0 = frag(vb_, row, quad);
            short8 v1 = frag(vb_, row, quad + 4);
            o[j2] = __builtin_amdgcn_mfma_f32_16x16x32_bf16(pf0, v0, o[j2], 0, 0, 0);
            o[j2] = __builtin_amdgcn_mfma_f32_16x16x32_bf16(pf1, v1, o[j2], 0, 0, 0);
        }
        bufi ^= 1;
    }

    // epilogue: divide by l, zero row q==0, stage + coalesced store
#pragma unroll
    for (int r = 0; r < 4; r++) {
        int qg = qr0 + quad * 4 + r;
        float linv = (qg == 0) ? 0.f : 1.f / lacc[r];
#pragma unroll
        for (int j2 = 0; j2 < 4; j2++)
            ps[wave][quad * 4 + r][j2 * 16 + fr] = f2bf(o[j2][r] * linv);
    }
    const int sub8 = (lane & 7) * 8;
    const int grp  = lane >> 3;
#pragma unroll
    for (int half = 0; half < 2; half++) {
        int rowl = half * 8 + grp;                   // 0..15
        short8 val = *(const short8*)&ps[wave][rowl][sub8];
        int qg = qr0 + rowl;
        *(short8*)&attnc[((size_t)qg * B_SZ + b) * H_DIM + h * DHEAD + sub8] = val;
    }
}

// ---------------------------------------------------------------------------
// LN1: reads bf16 X, writes bf16 out1 only (residual kept in bf16)
// ---------------------------------------------------------------------------
__global__ __launch_bounds__(256) void ln1_kernel(
    const ushort_t* __restrict__ X, const float* __restrict__ g,
    const float* __restrict__ bta, ushort_t* __restrict__ Yb)
{
    int m    = blockIdx.x * 4 + (threadIdx.x >> 6);
    int lane = threadIdx.x & 63;
    int c0   = lane * 8;
    const ushort_t* xr = X + (size_t)m * H_DIM + c0;
    float x[8];
    float s = 0.f, ss = 0.f;
    short8 xv = *(const short8*)xr;
#pragma unroll
    for (int i = 0; i < 8; i++) {
        x[i] = bf2f((ushort_t)xv[i]);
        s += x[i]; ss += x[i] * x[i];
    }
#pragma unroll
    for (int off = 32; off >= 1; off >>= 1) {
        s  += __shfl_xor(s,  off, 64);
        ss += __shfl_xor(ss, off, 64);
    }
    float mu  = s * (1.f / 512.f);
    float var = ss * (1.f / 512.f) - mu * mu;
    float rs  = rsqrtf(var + 1e-5f);
    ushort_t yb[8];
#pragma unroll
    for (int i = 0; i < 8; i++)
        yb[i] = f2bf((x[i] - mu) * rs * g[c0 + i] + bta[c0 + i]);
    *(short8*)(Yb + (size_t)m * H_DIM + c0) = *(short8*)&yb[0];
}

// ---------------------------------------------------------------------------
// LN2 + residual (bf16) + fused OW-dot
// ---------------------------------------------------------------------------
__global__ __launch_bounds__(256) void ln2_kernel(
    const ushort_t* __restrict__ X, const float* __restrict__ g,
    const float* __restrict__ bta, const ushort_t* __restrict__ res,
    ushort_t* __restrict__ pred_bf, const float* __restrict__ OW,
    float* __restrict__ lg)
{
    int m    = blockIdx.x * 4 + (threadIdx.x >> 6);
    int lane = threadIdx.x & 63;
    int c0   = lane * 8;
    const ushort_t* xr = X + (size_t)m * H_DIM + c0;
    float x[8];
    float s = 0.f, ss = 0.f;
    short8 xv = *(const short8*)xr;
#pragma unroll
    for (int i = 0; i < 8; i++) {
        x[i] = bf2f((ushort_t)xv[i]);
        s += x[i]; ss += x[i] * x[i];
    }
#pragma unroll
    for (int off = 32; off >= 1; off >>= 1) {
        s  += __shfl_xor(s,  off, 64);
        ss += __shfl_xor(ss, off, 64);
    }
    float mu  = s * (1.f / 512.f);
    float var = ss * (1.f / 512.f) - mu * mu;
    float rs  = rsqrtf(var + 1e-5f);
    short8 rv = *(const short8*)(res + (size_t)m * H_DIM + c0);
    ushort_t yb[8];
    float part = 0.f;
#pragma unroll
    for (int i = 0; i < 8; i++) {
        float v = (x[i] - mu) * rs * g[c0 + i] + bta[c0 + i] + bf2f((ushort_t)rv[i]);
        yb[i] = f2bf(v);
        part = fmaf(v, OW[c0 + i], part);
    }
    *(short8*)(pred_bf + (size_t)m * P_DIM + c0) = *(short8*)&yb[0];
#pragma unroll
    for (int off = 32; off >= 1; off >>= 1) part += __shfl_xor(part, off, 64);
    if (lane == 0) lg[m] += part;
}

// ---------------------------------------------------------------------------
__global__ __launch_bounds__(256) void bce_kernel(
    const float* __restrict__ lg, const int* __restrict__ labels,
    const float* __restrict__ mask, float* __restrict__ accum)
{
    int m    = blockIdx.x * 256 + threadIdx.x;
    int lane = threadIdx.x & 63;
    float l  = lg[m];
    float y  = (float)labels[m];
    float mv = mask[m];
    float a  = (fmaxf(l, 0.f) - l * y + log1pf(expf(-fabsf(l)))) * mv;
#pragma unroll
    for (int off = 32; off >= 1; off >>= 1) {
        a  += __shfl_xor(a,  off, 64);
        mv += __shfl_xor(mv, off, 64);
    }
    if (lane == 0) {
        atomicAdd(accum,     a);
        atomicAdd(accum + 1, mv);
    }
}

__global__ void finalize_kernel(const float* __restrict__ accum, float* __restrict__ out)
{
    out[0] = accum[0] / accum[1];
}

// ---------------------------------------------------------------------------
extern "C" void kernel_launch(void* const* d_in, const int* in_sizes, int n_in,
                              void* d_out, int out_size, void* d_ws, size_t ws_size,
                              hipStream_t stream)
{
    (void)in_sizes; (void)n_in; (void)out_size;
    const int*   ans    = (const int*)  d_in[0];
    const int*   cans   = (const int*)  d_in[1];
    const int*   labels = (const int*)  d_in[2];
    const float* mask   = (const float*)d_in[3];
    const int*   qids   = (const int*)  d_in[4];
    const int*   sids   = (const int*)  d_in[5];
    const float* smask  = (const float*)d_in[6];
    const float* Eq     = (const float*)d_in[7];
    const float* Es     = (const float*)d_in[8];
    const float* Ea     = (const float*)d_in[9];
    const float* El     = (const float*)d_in[10];
    const float* Wq     = (const float*)d_in[11];
    const float* bq     = (const float*)d_in[12];
    const float* Wk     = (const float*)d_in[13];
    const float* bk     = (const float*)d_in[14];
    const float* Wv     = (const float*)d_in[15];
    const float* bv     = (const float*)d_in[16];
    const float* Wo     = (const float*)d_in[17];
    const float* bo     = (const float*)d_in[18];
    const float* ln1_g  = (const float*)d_in[19];
    const float* ln1_b  = (const float*)d_in[20];
    const float* W1     = (const float*)d_in[21];
    const float* b1     = (const float*)d_in[22];
    const float* W2     = (const float*)d_in[23];
    const float* b2     = (const float*)d_in[24];
    const float* ln2_g  = (const float*)d_in[25];
    const float* ln2_b  = (const float*)d_in[26];
    const float* gammas = (const float*)d_in[27];
    const float* L1W    = (const float*)d_in[28];
    const float* L1b    = (const float*)d_in[29];
    const float* L2W    = (const float*)d_in[30];
    const float* L2b    = (const float*)d_in[31];
    const float* OW     = (const float*)d_in[32];
    const float* Ob     = (const float*)d_in[33];
    float* out = (float*)d_out;

    // Arena in units U = TB*64 floats (4 MiB). Peak ~176 MB.
    const size_t U = (size_t)TBTOK * 64;
    if (ws_size < 42 * U * sizeof(float)) return;
    float* ws = (float*)d_ws;
    ushort_t* wtb      = (ushort_t*)(ws);            // [0,3)  weights bf16 (perm)
    ushort_t* pred_bf  = (ushort_t*)(ws + 3 * U);    // [3,12) perm
    ushort_t* value_bf = (ushort_t*)(ws + 12 * U);   // [12,21) until V-gemm
    ushort_t* qb       = (ushort_t*)(ws + 21 * U);   // [21,25) until attn
    ushort_t* kb       = (ushort_t*)(ws + 25 * U);   // [25,29) until attn
    ushort_t* vtb      = (ushort_t*)(ws + 29 * U);   // [29,33) until attn
    ushort_t* attnc_bf = (ushort_t*)(ws + 33 * U);   // [33,37) until Wo
    ushort_t* x1_bf    = (ushort_t*)(ws + 12 * U);   // [12,16) Wo-out / LN1-in
    ushort_t* out1_bf  = (ushort_t*)(ws + 24 * U);   // [24,28) LN1..LN2 (bf16)
    ushort_t* f1_bf    = (ushort_t*)(ws + 28 * U);   // [28,32) W1-out
    ushort_t* f2_bf    = (ushort_t*)(ws + 32 * U);   // [32,36) W2-out / LN2-in
    ushort_t* h1_bf    = (ushort_t*)(ws + 12 * U);   // [12,22) L1-out (16384x1280)
    float*    lgits    = ws + 41 * U;                // TB floats
    float*    accum    = lgits + TBTOK;
    float*    OWp      = accum + 2;                  // padded head vecs (1280 ea)
    float*    L1bp     = OWp + P_PAD;
    float*    L2bp     = L1bp + P_PAD;

    // bf16 weight arena offsets (elements); wq||wk contiguous for merged QK
    ushort_t* wqk_b = wtb + 0;         // 1024 x 640
    ushort_t* wv_b  = wtb + 655360;
    ushort_t* wo_b  = wtb + 1245184;
    ushort_t* w1_b  = wtb + 1507328;
    ushort_t* w2_b  = wtb + 1769472;
    ushort_t* l1_b  = wtb + 2031616;   // 1280 x 1152 (padded rows)
    ushort_t* l2_b  = wtb + 3506176;   // 1280 x 1280 (padded rows+cols)

    convert_weights<<<1984, 256, 0, stream>>>(Wq, Wk, Wv, Wo, W1, W2, wtb, accum);
    pad_weights<<<3041, 256, 0, stream>>>(L1W, L2W, L1b, L2b, OW,
                                          l1_b, l2_b, L1bp, L2bp, OWp);
    // embeddings + fused logits tail dot
    embed_kernel<<<TBTOK, 256, 0, stream>>>(ans, cans, labels, mask, qids, sids,
                                            smask, Eq, Es, Ea, El, pred_bf, value_bf,
                                            OW, Ob, lgits);
    // merged Q|K projection (Q pre-scaled by 1/8): 128x256 tiles, 128x4 grid
    gemmT<4,5,false><<<dim3(128, 4), 512, 0, stream>>>(
        pred_bf + 512, P_DIM, wqk_b, 640, bq, bk, qb, kb, 0, 640, nullptr, nullptr);
    // V^T: 128x128 tiles, 128x4 grid, permuted A-row consumption
    gemmT<2,4,false><<<dim3(128, 4), 512, 0, stream>>>(
        value_bf, P_DIM, wv_b, P_DIM, bv, nullptr, vtb, nullptr, 0, P_DIM, nullptr, nullptr);
    // attention (MFMA flash, async LDS staging)
    attn_mfma<<<dim3(B_SZ * NHEAD, 8), 256, 0, stream>>>(
        qb, kb, vtb, mask, gammas, attnc_bf);
    // output projection -> x1_bf
    gemmT<2,1,false><<<dim3(128, 4), 512, 0, stream>>>(
        attnc_bf, H_DIM, wo_b, H_DIM, bo, nullptr, x1_bf, nullptr, H_DIM, H_DIM, nullptr, nullptr);
    ln1_kernel<<<TBTOK/4, 256, 0, stream>>>(x1_bf, ln1_g, ln1_b, out1_bf);
    // FFN
    gemmT<2,1,true><<<dim3(128, 4), 512, 0, stream>>>(
        out1_bf, H_DIM, w1_b, H_DIM, b1, nullptr, f1_bf, nullptr, H_DIM, H_DIM, nullptr, nullptr);
    gemmT<2,1,false><<<dim3(128, 4), 512, 0, stream>>>(
        f1_bf, H_DIM, w2_b, H_DIM, b2, nullptr, f2_bf, nullptr, H_DIM, H_DIM, nullptr, nullptr);
    // LN2 + bf16 residual + fused head-dot into lgits
    ln2_kernel<<<TBTOK/4, 256, 0, stream>>>(f2_bf, ln2_g, ln2_b, out1_bf, pred_bf, OW, lgits);
    // L1 (relu) -> h1 [16384][1280]: 128x320 tiles, 128x4 grid
    gemmT<5,1,true><<<dim3(128, 4), 512, 0, stream>>>(
        pred_bf, P_DIM, l1_b, P_DIM, L1bp, nullptr, h1_bf, nullptr, P_PAD, P_DIM, nullptr, nullptr);
    // L2 (relu) fused with OW dot -> atomics into lgits
    gemmT<5,3,true><<<dim3(128, 4), 512, 0, stream>>>(
        h1_bf, P_PAD, l2_b, P_PAD, L2bp, nullptr, nullptr, nullptr, 0, P_PAD, OWp, lgits);
    // BCE + reduction
    bce_kernel<<<TBTOK/256, 256, 0, stream>>>(lgits, labels, mask, accum);
    finalize_kernel<<<1, 1, 0, stream>>>(accum, out);
}

// Round 11
// 447.890 us; speedup vs baseline: 1.0346x; 1.0346x over previous
//
#include <hip/hip_runtime.h>
#include <math.h>

// Problem constants
#define T_LEN 512
#define B_SZ  32
#define NHEAD 8
#define DHEAD 64
#define H_DIM 512
#define TBTOK 16384          // T*B
#define P_DIM 1152
#define P_PAD 1280           // P padded for the 320-wide gemm

typedef unsigned short ushort_t;
typedef short short8 __attribute__((ext_vector_type(8)));
typedef float f32x4 __attribute__((ext_vector_type(4)));

__device__ __forceinline__ ushort_t f2bf(float f) {
    union { float f; unsigned int u; } v; v.f = f;
    unsigned int r = v.u + 0x7fffu + ((v.u >> 16) & 1u);
    return (ushort_t)(r >> 16);
}
__device__ __forceinline__ float bf2f(ushort_t h) {
    union { unsigned int u; float f; } v; v.u = ((unsigned int)h) << 16;
    return v.f;
}
__device__ __forceinline__ void gload_lds16(const void* g, void* l) {
    __builtin_amdgcn_global_load_lds(
        (const __attribute__((address_space(1))) void*)g,
        (__attribute__((address_space(3))) void*)l, 16, 0, 0);
}

// ---------------------------------------------------------------------------
// Weight fp32 -> bf16 packing (first 6 matrices, flat) + accum zero
// ---------------------------------------------------------------------------
__global__ __launch_bounds__(256) void convert_weights(
    const float* __restrict__ wq, const float* __restrict__ wk,
    const float* __restrict__ wv, const float* __restrict__ wo,
    const float* __restrict__ w1, const float* __restrict__ w2,
    ushort_t* __restrict__ dst, float* __restrict__ accum)
{
    if (blockIdx.x == 0 && threadIdx.x < 2) accum[threadIdx.x] = 0.f;
    const unsigned int offs[7] = {0u, 327680u, 655360u, 1245184u, 1507328u,
                                  1769472u, 2031616u};
    unsigned int c = (blockIdx.x * 256 + threadIdx.x) * 4;   // element offset
    const float* srcs[6] = {wq, wk, wv, wo, w1, w2};
    int s = 0;
#pragma unroll
    for (int i = 0; i < 5; i++) s += (c >= offs[i + 1]) ? 1 : 0;
    float4 v = *(const float4*)(srcs[s] + (c - offs[s]));
    ushort4 o;
    o.x = f2bf(v.x); o.y = f2bf(v.y); o.z = f2bf(v.z); o.w = f2bf(v.w);
    *(ushort4*)(dst + c) = o;
}

// ---------------------------------------------------------------------------
// L1W -> [1280][1152] bf16 (zero pad rows), L2W -> [1280][1280] bf16
// (zero pad rows+cols), plus padded L1b/L2b/OW float vectors (1280).
// ---------------------------------------------------------------------------
__global__ __launch_bounds__(256) void pad_weights(
    const float* __restrict__ l1, const float* __restrict__ l2,
    const float* __restrict__ L1b, const float* __restrict__ L2b,
    const float* __restrict__ OW,
    ushort_t* __restrict__ l1d, ushort_t* __restrict__ l2d,
    float* __restrict__ L1bp, float* __restrict__ L2bp, float* __restrict__ OWp)
{
    int blk = blockIdx.x;
    if (blk < 1440) {                       // l1: 1280*1152 = 1,474,560 elems
        int o4 = (blk * 256 + threadIdx.x) * 4;
        int row = o4 / 1152;
        int col = o4 - row * 1152;
        ushort4 o; o.x = 0; o.y = 0; o.z = 0; o.w = 0;
        if (row < 1152) {
            float4 v = *(const float4*)(l1 + (size_t)row * 1152 + col);
            o.x = f2bf(v.x); o.y = f2bf(v.y); o.z = f2bf(v.z); o.w = f2bf(v.w);
        }
        *(ushort4*)(l1d + o4) = o;
    } else if (blk < 3040) {                // l2: 1280*1280 = 1,638,400 elems
        int o4 = ((blk - 1440) * 256 + threadIdx.x) * 4;
        int row = o4 / 1280;
        int col = o4 - row * 1280;
        ushort4 o; o.x = 0; o.y = 0; o.z = 0; o.w = 0;
        if (row < 1152 && col < 1152) {     // 4-chunk never straddles 1152 (4|1152)
            float4 v = *(const float4*)(l2 + (size_t)row * 1152 + col);
            o.x = f2bf(v.x); o.y = f2bf(v.y); o.z = f2bf(v.z); o.w = f2bf(v.w);
        }
        *(ushort4*)(l2d + o4) = o;
    } else {
        for (int i = threadIdx.x; i < P_PAD; i += 256) {
            L1bp[i] = (i < P_DIM) ? L1b[i] : 0.f;
            L2bp[i] = (i < P_DIM) ? L2b[i] : 0.f;
            OWp[i]  = (i < P_DIM) ? OW[i]  : 0.f;
        }
    }
}

// ---------------------------------------------------------------------------
// Embedding / gather (bf16 outputs) + fused logits tail dot
// ---------------------------------------------------------------------------
__global__ __launch_bounds__(256) void embed_kernel(
    const int* __restrict__ ans, const int* __restrict__ cans,
    const int* __restrict__ labels, const float* __restrict__ mask,
    const int* __restrict__ qids, const int* __restrict__ sids,
    const float* __restrict__ smask,
    const float* __restrict__ Eq, const float* __restrict__ Es,
    const float* __restrict__ Ea, const float* __restrict__ El,
    ushort_t* __restrict__ pred_bf, ushort_t* __restrict__ value_bf,
    const float* __restrict__ OW, const float* __restrict__ Ob,
    float* __restrict__ lgits)
{
    __shared__ float red[4];
    int m = blockIdx.x;              // token = t*B + b
    int tid = threadIdx.x;           // 256
    float mval = mask[m];
    int qid = qids[m];
    int a   = ans[m] - 1;
    int ca  = cans[m] - 1;
    int lb  = labels[m];
    ushort_t* pr = pred_bf  + (size_t)m * P_DIM;
    ushort_t* vr = value_bf + (size_t)m * P_DIM;

    float part = 0.f;
    if (tid < 128) {
        ushort_t qv = f2bf(Eq[(size_t)qid * 128 + tid]);
        pr[512 + tid] = qv;
        vr[768 + tid] = qv;
        part = bf2f(qv) * OW[512 + tid];
    }
    int d = tid;                     // 0..255
    float s = 0.f;
#pragma unroll
    for (int j = 0; j < 8; j++) {
        int  sid = sids[m * 8 + j];
        float sm = smask[m * 8 + j];
        s += Es[(size_t)sid * 256 + d] * sm;
    }
    ushort_t sb = f2bf(s);
    pr[640 + d] = sb;
    vr[896 + d] = sb;
    ushort_t cab = f2bf(Ea[ca * 256 + d]);
    pr[896 + d] = cab;
    vr[512 + d] = cab;
    vr[256 + d] = f2bf(Ea[a * 256 + d] * mval);
    vr[0   + d] = f2bf(El[lb * 256 + d] * mval);

    part = fmaf(bf2f(sb),  OW[640 + d], part);
    part = fmaf(bf2f(cab), OW[896 + d], part);
#pragma unroll
    for (int off = 32; off >= 1; off >>= 1) part += __shfl_xor(part, off, 64);
    if ((tid & 63) == 0) red[tid >> 6] = part;
    __syncthreads();
    if (tid == 0) lgits[m] = red[0] + red[1] + red[2] + red[3] + Ob[0];
}

// ---------------------------------------------------------------------------
// TLP-overlapped MFMA GEMM (r20 = r10 loop + de-atomic MODE 3).
// 128 x (64*JC) tile, BK=64, 512 thr = 8 waves (2M x 4N), per-wave C =
// 64 x (16*JC) (acc[4][JC]). Grid = 128 x 4 = 512 wgs = 2+ blocks/CU
// (m114 TLP: co-resident block's MFMA hides this block's stage-wait /
// read-burst). LDS khalf layout (r11-verified, 164K conflicts): A
// 2x128x32, B 2xBNx32; DMA roll (row>>1)&3, frag read csw.
// Serial loop: stage both khalves -> vmcnt(0) -> barrier -> compute
// kh0,kh1 -> barrier.
// r20 (r10 post-mortem): MODE 3's atomicAdd into lg[] was the 99MB
// WRITE_SIZE / 86us regression -- 16 cross-XCD atomics per row bounce
// cache lines (device-scope, non-coherent per-XCD L2). Replaced with:
// intra-block LDS reduce over the 4 wn-waves, then ONE contiguous
// 512B store per block into part[by][m]; bce sums the 4 partials.
// No global RMW anywhere in the GEMM path now.
// MODE 1: bias + optional relu, bf16 row-major store (ldc)
// MODE 3: bias + relu, dot with OW, per-block partial -> lg[by*TBTOK+m]
// MODE 4: JC=2, V^T scatter [bh][d][t]; A rows consumed (b,t)-permuted
// MODE 5: JC=4, merged Q|K scatter [bh][t][d]
// Epilogue stages alias SH (all waves past final barrier; wave-private).
// ---------------------------------------------------------------------------
template<int JC, int MODE, bool RELU>
__global__ __launch_bounds__(512, 4) void gemmT(
    const ushort_t* __restrict__ A, int lda,
    const ushort_t* __restrict__ W, int ldw,
    const float* __restrict__ bias, const float* __restrict__ bias2,
    ushort_t* __restrict__ Cb, ushort_t* __restrict__ Cb2, int ldc, int K,
    const float* __restrict__ OW, float* __restrict__ lg)
{
    constexpr int BN = JC * 64;
    // [A kh0][A kh1][B kh0][B kh1], rows of 32 ushorts
    __shared__ __align__(16) ushort_t SH[2 * 128 * 32 + 2 * BN * 32];
    ushort_t* Bs0 = SH + 2 * 128 * 32;

    const int m0 = blockIdx.x * 128;
    const int n0 = blockIdx.y * BN;
    const int wave = threadIdx.x >> 6;
    const int lane = threadIdx.x & 63;
    const int wm = wave >> 2, wn = wave & 3;   // 2M x 4N waves
    const int fr   = lane & 15;
    const int quad = lane >> 4;
    // frag read roll (r11-verified): row mod 16 == fr -> (row>>1)&3 ==
    // (fr>>1)&3 (row bases wm*64,i*16,wn*JC*16,j*16 all mult of 8 elems)
    const int csw  = ((quad + ((fr >> 1) & 3)) & 3) * 8;

    // staging: instr covers 16 rows of 32 ushorts; lane -> row +(lane>>2),
    // phys chunk lane&3, source chunk ((lane&3)-((slr>>1)&3))&3 (row-block
    // bases are mult of 16 -> drop out of the roll).
    const int slr = lane >> 2;
    const int sc  = (((lane & 3) - ((slr >> 1) & 3)) & 3) * 8;
    const ushort_t* Asrc;
    size_t aRS;   // A address stride per +1 staged row
    if (MODE == 4) {
        // token(r) = ((m0&511)+r)*32 + (m0>>9); affine in r (128 | m0)
        Asrc = A + (size_t)(((m0 & 511) + slr) * 32 + (m0 >> 9)) * lda + sc;
        aRS  = (size_t)32 * lda;
    } else {
        Asrc = A + (size_t)(m0 + slr) * lda + sc;
        aRS  = (size_t)lda;
    }
    const ushort_t* Wsrc = W + (size_t)(n0 + slr) * ldw + sc;
    const int NT = K >> 6;

    auto stA = [&](int t, int kh) {      // 8 instrs: 1 per wave (128 rows)
        int rb = wave * 16;
        gload_lds16(Asrc + (size_t)rb * aRS + (t * 64 + kh * 32),
                    &SH[(kh * 128 + rb) * 32]);
    };
    auto stB = [&](int t, int kh) {      // 4*JC instrs (BN rows)
#pragma unroll
        for (int n = 0; n < JC / 2; n++) {
            int rb = (wave + 8 * n) * 16;
            gload_lds16(Wsrc + (size_t)rb * ldw + (t * 64 + kh * 32),
                        &Bs0[(kh * BN + rb) * 32]);
        }
        if (JC & 1) {
            if (wave < 4) {
                int rb = (wave + 8 * (JC / 2)) * 16;
                gload_lds16(Wsrc + (size_t)rb * ldw + (t * 64 + kh * 32),
                            &Bs0[(kh * BN + rb) * 32]);
            }
        }
    };

    f32x4 acc[4][JC] = {};

    for (int t = 0; t < NT; ++t) {
        stA(t, 0); stA(t, 1); stB(t, 0); stB(t, 1);
        asm volatile("s_waitcnt vmcnt(0)" ::: "memory");
        __builtin_amdgcn_s_barrier();
#pragma unroll
        for (int kh = 0; kh < 2; kh++) {
            const ushort_t* Ar = &SH[(kh * 128) * 32];
            const ushort_t* Br = &Bs0[(kh * BN) * 32];
            short8 af[4], bf[JC];
#pragma unroll
            for (int i = 0; i < 4; i++)
                af[i] = *(const short8*)&Ar[(wm * 64 + i * 16 + fr) * 32 + csw];
#pragma unroll
            for (int j = 0; j < JC; j++)
                bf[j] = *(const short8*)&Br[(wn * (JC * 16) + j * 16 + fr) * 32 + csw];
#pragma unroll
            for (int i = 0; i < 4; i++)
#pragma unroll
                for (int j = 0; j < JC; j++)
                    acc[i][j] = __builtin_amdgcn_mfma_f32_16x16x32_bf16(
                        af[i], bf[j], acc[i][j], 0, 0, 0);
        }
        __builtin_amdgcn_s_barrier();    // all reads done before next stage
    }

    // C/D layout per frag: col = fr, row = quad*4 + reg.
    // acc[ii][j] -> row = m0 + wm*64 + ii*16 + quad*4 + r
    const int nbase = n0 + wn * (JC * 16);

    if (MODE == 3) {
        // de-atomic epilogue: per-row partial -> LDS wn-plane -> one
        // contiguous per-block store into lg[by*TBTOK + m0 + rl].
        float* shp = (float*)SH;               // [4 wn][128 rl] floats
#pragma unroll
        for (int ii = 0; ii < 4; ii++)
#pragma unroll
            for (int r = 0; r < 4; r++) {
                int rl = wm * 64 + ii * 16 + quad * 4 + r;
                float part = 0.f;
#pragma unroll
                for (int j = 0; j < JC; j++) {
                    int col = nbase + j * 16 + fr;
                    float v = fmaxf(acc[ii][j][r] + bias[col], 0.f);
                    part = fmaf(v, OW[col], part);
                }
                part += __shfl_xor(part, 1, 64);
                part += __shfl_xor(part, 2, 64);
                part += __shfl_xor(part, 4, 64);
                part += __shfl_xor(part, 8, 64);
                if (fr == 0) shp[wn * 128 + rl] = part;
            }
        __syncthreads();
        int tid = threadIdx.x;
        if (tid < 128) {
            float v = shp[tid] + shp[128 + tid] + shp[256 + tid] + shp[384 + tid];
            lg[(size_t)blockIdx.y * TBTOK + m0 + tid] = v;
        }
        return;
    }

    if (MODE == 5) {
        // JC=4: per-wave 64 rows x 64 cols = one head's d-range.
        bool side = (nbase >= 512);
        const float* bp = side ? bias2 : bias;
        const int boff  = nbase & 511;
        const float scl = side ? 1.f : 0.125f;
        ushort_t* base  = side ? Cb2 : Cb;
        const int h = (nbase >> 6) & 7;
        ushort_t* etw = SH + wave * (16 * 72);
#pragma unroll
        for (int ii = 0; ii < 4; ii++) {
#pragma unroll
            for (int r = 0; r < 4; r++)
#pragma unroll
                for (int j = 0; j < 4; j++) {
                    float v = (acc[ii][j][r] + bp[boff + j * 16 + fr]) * scl;
                    etw[(quad * 4 + r) * 72 + j * 16 + fr] = f2bf(v);
                }
            int rowb = m0 + wm * 64 + ii * 16;
#pragma unroll
            for (int u = lane; u < 128; u += 64) {
                int rr = u >> 3, cc = (u & 7) * 8;
                int row = rowb + rr;            // token m = t*32 + b
                int tq = row >> 5, b = row & 31;
                short8 val = *(const short8*)&etw[rr * 72 + cc];
                *(short8*)&base[(((size_t)(b * 8 + h)) << 15) + ((size_t)tq << 6) + cc] = val;
            }
        }
        return;
    }

    if (MODE == 4) {
        // JC=2: per-wave 64 rows(m=b*512+t, same b) x 32 cols(d).
        // Transposed stage per 32-t half: 32 d x 32 t, scatter to
        // vtb[bh][d][512].
        ushort_t* etw = SH + wave * (32 * 40);
        const int h = nbase >> 6;
        const int dbase = nbase & 63;
        const int mbase = m0 + wm * 64;
        const int b = mbase >> 9;
        size_t obase0 = (((size_t)(b * 8 + h)) << 15) + ((size_t)dbase << 9)
                        + (mbase & 511);
#pragma unroll
        for (int p = 0; p < 2; p++) {
#pragma unroll
            for (int iiL = 0; iiL < 2; iiL++) {
                int ii = p * 2 + iiL;
#pragma unroll
                for (int r = 0; r < 4; r++) {
                    int rl = iiL * 16 + quad * 4 + r;    // t-offset 0..31
#pragma unroll
                    for (int j = 0; j < 2; j++) {
                        int cl = j * 16 + fr;            // d-offset 0..31
                        float v = acc[ii][j][r] + bias[nbase + cl];
                        etw[cl * 40 + rl] = f2bf(v);
                    }
                }
            }
            size_t obase = obase0 + p * 32;
#pragma unroll
            for (int u = lane; u < 128; u += 64) {
                int dr = u >> 2, cc = (u & 3) * 8;
                short8 val = *(const short8*)&etw[dr * 40 + cc];
                *(short8*)&Cb[obase + ((size_t)dr << 9) + cc] = val;
            }
        }
        return;
    }

    // MODE 1: per-ii stage 16 rows x JC*16 cols in wave-private LDS slice
    // (aliased onto SH), then coalesced short8 stores.
    {
        constexpr int STR = JC * 16 + 8;
        constexpr int CPR = 2 * JC;            // short8 chunks per row
        ushort_t* etw = SH + wave * (16 * STR);
#pragma unroll
        for (int ii = 0; ii < 4; ii++) {
#pragma unroll
            for (int r = 0; r < 4; r++)
#pragma unroll
                for (int j = 0; j < JC; j++) {
                    float v = acc[ii][j][r] + bias[nbase + j * 16 + fr];
                    if (RELU) v = fmaxf(v, 0.f);
                    etw[(quad * 4 + r) * STR + j * 16 + fr] = f2bf(v);
                }
            int rowb = m0 + wm * 64 + ii * 16;
#pragma unroll
            for (int u = lane; u < 16 * CPR; u += 64) {
                int rr = u / CPR;
                int cc = u - rr * CPR;
                short8 val = *(const short8*)&etw[rr * STR + cc * 8];
                *(short8*)&Cb[(size_t)(rowb + rr) * ldc + nbase + cc * 8] = val;
            }
        }
    }
}

// ---------------------------------------------------------------------------
// MFMA flash attention, no-rescale softmax, cooperative async K/V LDS staging
// ---------------------------------------------------------------------------
__global__ __launch_bounds__(256) void attn_mfma(
    const ushort_t* __restrict__ qb, const ushort_t* __restrict__ kb,
    const ushort_t* __restrict__ vtb, const float* __restrict__ mask,
    const float* __restrict__ gammas, ushort_t* __restrict__ attnc)
{
    __shared__ __align__(16) ushort_t kbuf[2][64 * 64];  // 16 KB
    __shared__ __align__(16) ushort_t vbuf[2][64 * 64];  // 16 KB
    __shared__ __align__(16) ushort_t ps[4][16][72];     // P / O stage, per wave
    __shared__ float decayF[512];
    __shared__ float mneg[512];

    const int bh  = blockIdx.x;          // b*8 + h
    const int b   = bh >> 3;
    const int h   = bh & 7;
    const int qt0 = (7 - blockIdx.y) * 64;   // heavy tiles first
    const int tid  = threadIdx.x;
    const int wave = tid >> 6;
    const int lane = tid & 63;
    const int fr   = lane & 15;
    const int quad = lane >> 4;

    {   // LUTs: decay' = clip(exp(-sp*sqrt(d)),1e-5,..)*log2e ; mneg = 0/-1e32
        float g  = gammas[h];
        float sp = (g > 20.f) ? g : log1pf(expf(g));
        for (int i = tid; i < 512; i += 256) {
            decayF[i] = fmaxf(exp2f(-sp * 1.44269504f * sqrtf((float)i)), 1e-5f)
                        * 1.44269504f;
            mneg[i]   = (mask[(size_t)i * B_SZ + b] == 0.f) ? -1e32f : 0.f;
        }
    }

    const int qr0 = qt0 + wave * 16;
    const ushort_t* qbase = qb  + ((size_t)bh << 15);   // [t][64]
    const ushort_t* kbase = kb  + ((size_t)bh << 15);
    const ushort_t* vbase = vtb + ((size_t)bh << 15);   // [d][512]

    short8 af0 = *(const short8*)(qbase + (size_t)(qr0 + fr) * 64 + quad * 8);
    short8 af1 = *(const short8*)(qbase + (size_t)(qr0 + fr) * 64 + 32 + quad * 8);
    const short8 ones = {0x3F80, 0x3F80, 0x3F80, 0x3F80,
                         0x3F80, 0x3F80, 0x3F80, 0x3F80};

    const int rl0 = wave * 16 + (lane >> 3);
    const int rl1 = rl0 + 8;
    const int sc0 = (((lane & 7) - rl0) & 7) * 8;   // ushort offset
    const int sc1 = (((lane & 7) - rl1) & 7) * 8;

    auto stage = [&](int kt, int bufi) {
        gload_lds16(kbase + (size_t)(kt + rl0) * 64 + sc0, &kbuf[bufi][(wave * 16) * 64]);
        gload_lds16(kbase + (size_t)(kt + rl1) * 64 + sc1, &kbuf[bufi][(wave * 16 + 8) * 64]);
        gload_lds16(vbase + (size_t)rl0 * T_LEN + kt + sc0, &vbuf[bufi][(wave * 16) * 64]);
        gload_lds16(vbase + (size_t)rl1 * T_LEN + kt + sc1, &vbuf[bufi][(wave * 16 + 8) * 64]);
    };
    auto frag = [&](const ushort_t* buf, int row, int lchunk) -> short8 {
        return *(const short8*)&buf[row * 64 + ((lchunk + row) & 7) * 8];
    };

    stage(0, 0);

    f32x4 o[4] = {};                    // O[q=quad*4+r][d=j2*16+fr]
    f32x4 lacc = {};                    // row sums, same layout rows
    int bufi = 0;

    for (int kt0 = 0; kt0 <= qt0; kt0 += 64) {
        __syncthreads();                // drains staged loads; buffer handoff
        if (kt0 < qt0) stage(kt0 + 64, bufi ^ 1);   // prefetch during compute
        const bool diag = (kt0 == qt0);
        const ushort_t* kb_ = kbuf[bufi];
        const ushort_t* vb_ = vbuf[bufi];

        // ---- S = Q K^T (16 x 64) ----
        f32x4 sacc[4] = {};
#pragma unroll
        for (int j = 0; j < 4; j++) {
            int row = j * 16 + fr;
            short8 k0 = frag(kb_, row, quad);
            short8 k1 = frag(kb_, row, quad + 4);
            sacc[j] = __builtin_amdgcn_mfma_f32_16x16x32_bf16(af0, k0, sacc[j], 0, 0, 0);
            sacc[j] = __builtin_amdgcn_mfma_f32_16x16x32_bf16(af1, k1, sacc[j], 0, 0, 0);
        }

        // ---- softmax (no rescale): p = exp2(fma(s, decay', mneg)) ----
#pragma unroll
        for (int j = 0; j < 4; j++) {
            int kg = kt0 + j * 16 + fr;
            float mn = mneg[kg];
            int qgb = qr0 + quad * 4;
            if (!diag) {
                int base = qgb - kg;
#pragma unroll
                for (int r = 0; r < 4; r++) {
                    float t = fmaf(sacc[j][r], decayF[base + r], mn);
                    union { float f; unsigned u; } cv; cv.f = exp2f(t);
                    ps[wave][quad * 4 + r][j * 16 + fr] = (ushort_t)(cv.u >> 16);
                }
            } else {
#pragma unroll
                for (int r = 0; r < 4; r++) {
                    int didx = qgb + r - kg;
                    float dec = decayF[didx > 0 ? didx : 0];
                    float t = fmaf(sacc[j][r], dec, mn);
                    if (didx <= 0) t = -1e32f;      // causal (kg >= qg)
                    union { float f; unsigned u; } cv; cv.f = exp2f(t);
                    ps[wave][quad * 4 + r][j * 16 + fr] = (ushort_t)(cv.u >> 16);
                }
            }
        }
        short8 pf0 = *(const short8*)&ps[wave][fr][quad * 8];
        short8 pf1 = *(const short8*)&ps[wave][fr][32 + quad * 8];
        lacc = __builtin_amdgcn_mfma_f32_16x16x32_bf16(pf0, ones, lacc, 0, 0, 0);
        lacc = __builtin_amdgcn_mfma_f32_16x16x32_bf16(pf1, ones, lacc, 0, 0, 0);
#pragma unroll
        for (int j2 = 0; j2 < 4; j2++) {
            int row = j2 * 16 + fr;
            short8 v0 = frag(vb_, row, quad);
            short8 v1 = frag(vb_, row, quad + 4);
            o[j2] = __builtin_amdgcn_mfma_f32_16x16x32_bf16(pf0, v0, o[j2], 0, 0, 0);
            o[j2] = __builtin_amdgcn_mfma_f32_16x16x32_bf16(pf1, v1, o[j2], 0, 0, 0);
        }
        bufi ^= 1;
    }

    // epilogue: divide by l, zero row q==0, stage + coalesced store
#pragma unroll
    for (int r = 0; r < 4; r++) {
        int qg = qr0 + quad * 4 + r;
        float linv = (qg == 0) ? 0.f : 1.f / lacc[r];
#pragma unroll
        for (int j2 = 0; j2 < 4; j2++)
            ps[wave][quad * 4 + r][j2 * 16 + fr] = f2bf(o[j2][r] * linv);
    }
    const int sub8 = (lane & 7) * 8;
    const int grp  = lane >> 3;
#pragma unroll
    for (int half = 0; half < 2; half++) {
        int rowl = half * 8 + grp;                   // 0..15
        short8 val = *(const short8*)&ps[wave][rowl][sub8];
        int qg = qr0 + rowl;
        *(short8*)&attnc[((size_t)qg * B_SZ + b) * H_DIM + h * DHEAD + sub8] = val;
    }
}

// ---------------------------------------------------------------------------
// LN1: reads bf16 X, writes bf16 out1 only (residual kept in bf16)
// ---------------------------------------------------------------------------
__global__ __launch_bounds__(256) void ln1_kernel(
    const ushort_t* __restrict__ X, const float* __restrict__ g,
    const float* __restrict__ bta, ushort_t* __restrict__ Yb)
{
    int m    = blockIdx.x * 4 + (threadIdx.x >> 6);
    int lane = threadIdx.x & 63;
    int c0   = lane * 8;
    const ushort_t* xr = X + (size_t)m * H_DIM + c0;
    float x[8];
    float s = 0.f, ss = 0.f;
    short8 xv = *(const short8*)xr;
#pragma unroll
    for (int i = 0; i < 8; i++) {
        x[i] = bf2f((ushort_t)xv[i]);
        s += x[i]; ss += x[i] * x[i];
    }
#pragma unroll
    for (int off = 32; off >= 1; off >>= 1) {
        s  += __shfl_xor(s,  off, 64);
        ss += __shfl_xor(ss, off, 64);
    }
    float mu  = s * (1.f / 512.f);
    float var = ss * (1.f / 512.f) - mu * mu;
    float rs  = rsqrtf(var + 1e-5f);
    ushort_t yb[8];
#pragma unroll
    for (int i = 0; i < 8; i++)
        yb[i] = f2bf((x[i] - mu) * rs * g[c0 + i] + bta[c0 + i]);
    *(short8*)(Yb + (size_t)m * H_DIM + c0) = *(short8*)&yb[0];
}

// ---------------------------------------------------------------------------
// LN2 + residual (bf16) + fused OW-dot
// ---------------------------------------------------------------------------
__global__ __launch_bounds__(256) void ln2_kernel(
    const ushort_t* __restrict__ X, const float* __restrict__ g,
    const float* __restrict__ bta, const ushort_t* __restrict__ res,
    ushort_t* __restrict__ pred_bf, const float* __restrict__ OW,
    float* __restrict__ lg)
{
    int m    = blockIdx.x * 4 + (threadIdx.x >> 6);
    int lane = threadIdx.x & 63;
    int c0   = lane * 8;
    const ushort_t* xr = X + (size_t)m * H_DIM + c0;
    float x[8];
    float s = 0.f, ss = 0.f;
    short8 xv = *(const short8*)xr;
#pragma unroll
    for (int i = 0; i < 8; i++) {
        x[i] = bf2f((ushort_t)xv[i]);
        s += x[i]; ss += x[i] * x[i];
    }
#pragma unroll
    for (int off = 32; off >= 1; off >>= 1) {
        s  += __shfl_xor(s,  off, 64);
        ss += __shfl_xor(ss, off, 64);
    }
    float mu  = s * (1.f / 512.f);
    float var = ss * (1.f / 512.f) - mu * mu;
    float rs  = rsqrtf(var + 1e-5f);
    short8 rv = *(const short8*)(res + (size_t)m * H_DIM + c0);
    ushort_t yb[8];
    float part = 0.f;
#pragma unroll
    for (int i = 0; i < 8; i++) {
        float v = (x[i] - mu) * rs * g[c0 + i] + bta[c0 + i] + bf2f((ushort_t)rv[i]);
        yb[i] = f2bf(v);
        part = fmaf(v, OW[c0 + i], part);
    }
    *(short8*)(pred_bf + (size_t)m * P_DIM + c0) = *(short8*)&yb[0];
#pragma unroll
    for (int off = 32; off >= 1; off >>= 1) part += __shfl_xor(part, off, 64);
    if (lane == 0) lg[m] += part;
}

// ---------------------------------------------------------------------------
// BCE: logit = lg[m] + sum of 4 per-by L2 partials (de-atomic path)
// ---------------------------------------------------------------------------
__global__ __launch_bounds__(256) void bce_kernel(
    const float* __restrict__ lg, const float* __restrict__ p4,
    const int* __restrict__ labels, const float* __restrict__ mask,
    float* __restrict__ accum)
{
    int m    = blockIdx.x * 256 + threadIdx.x;
    int lane = threadIdx.x & 63;
    float l  = lg[m] + p4[m] + p4[TBTOK + m] + p4[2 * TBTOK + m]
             + p4[3 * TBTOK + m];
    float y  = (float)labels[m];
    float mv = mask[m];
    float a  = (fmaxf(l, 0.f) - l * y + log1pf(expf(-fabsf(l)))) * mv;
#pragma unroll
    for (int off = 32; off >= 1; off >>= 1) {
        a  += __shfl_xor(a,  off, 64);
        mv += __shfl_xor(mv, off, 64);
    }
    if (lane == 0) {
        atomicAdd(accum,     a);
        atomicAdd(accum + 1, mv);
    }
}

__global__ void finalize_kernel(const float* __restrict__ accum, float* __restrict__ out)
{
    out[0] = accum[0] / accum[1];
}

// ---------------------------------------------------------------------------
extern "C" void kernel_launch(void* const* d_in, const int* in_sizes, int n_in,
                              void* d_out, int out_size, void* d_ws, size_t ws_size,
                              hipStream_t stream)
{
    (void)in_sizes; (void)n_in; (void)out_size;
    const int*   ans    = (const int*)  d_in[0];
    const int*   cans   = (const int*)  d_in[1];
    const int*   labels = (const int*)  d_in[2];
    const float* mask   = (const float*)d_in[3];
    const int*   qids   = (const int*)  d_in[4];
    const int*   sids   = (const int*)  d_in[5];
    const float* smask  = (const float*)d_in[6];
    const float* Eq     = (const float*)d_in[7];
    const float* Es     = (const float*)d_in[8];
    const float* Ea     = (const float*)d_in[9];
    const float* El     = (const float*)d_in[10];
    const float* Wq     = (const float*)d_in[11];
    const float* bq     = (const float*)d_in[12];
    const float* Wk     = (const float*)d_in[13];
    const float* bk     = (const float*)d_in[14];
    const float* Wv     = (const float*)d_in[15];
    const float* bv     = (const float*)d_in[16];
    const float* Wo     = (const float*)d_in[17];
    const float* bo     = (const float*)d_in[18];
    const float* ln1_g  = (const float*)d_in[19];
    const float* ln1_b  = (const float*)d_in[20];
    const float* W1     = (const float*)d_in[21];
    const float* b1     = (const float*)d_in[22];
    const float* W2     = (const float*)d_in[23];
    const float* b2     = (const float*)d_in[24];
    const float* ln2_g  = (const float*)d_in[25];
    const float* ln2_b  = (const float*)d_in[26];
    const float* gammas = (const float*)d_in[27];
    const float* L1W    = (const float*)d_in[28];
    const float* L1b    = (const float*)d_in[29];
    const float* L2W    = (const float*)d_in[30];
    const float* L2b    = (const float*)d_in[31];
    const float* OW     = (const float*)d_in[32];
    const float* Ob     = (const float*)d_in[33];
    float* out = (float*)d_out;

    // Arena in units U = TB*64 floats (4 MiB). Peak ~176 MB.
    const size_t U = (size_t)TBTOK * 64;
    if (ws_size < 42 * U * sizeof(float)) return;
    float* ws = (float*)d_ws;
    ushort_t* wtb      = (ushort_t*)(ws);            // [0,3)  weights bf16 (perm)
    ushort_t* pred_bf  = (ushort_t*)(ws + 3 * U);    // [3,12) perm
    ushort_t* value_bf = (ushort_t*)(ws + 12 * U);   // [12,21) until V-gemm
    ushort_t* qb       = (ushort_t*)(ws + 21 * U);   // [21,25) until attn
    ushort_t* kb       = (ushort_t*)(ws + 25 * U);   // [25,29) until attn
    ushort_t* vtb      = (ushort_t*)(ws + 29 * U);   // [29,33) until attn
    ushort_t* attnc_bf = (ushort_t*)(ws + 33 * U);   // [33,37) until Wo
    ushort_t* x1_bf    = (ushort_t*)(ws + 12 * U);   // [12,16) Wo-out / LN1-in
    ushort_t* out1_bf  = (ushort_t*)(ws + 24 * U);   // [24,28) LN1..LN2 (bf16)
    ushort_t* f1_bf    = (ushort_t*)(ws + 28 * U);   // [28,32) W1-out
    ushort_t* f2_bf    = (ushort_t*)(ws + 32 * U);   // [32,36) W2-out / LN2-in
    ushort_t* h1_bf    = (ushort_t*)(ws + 12 * U);   // [12,22) L1-out (16384x1280)
    float*    l2part   = ws + 40 * U;                // [40,41) 4 x TB partials
    float*    lgits    = ws + 41 * U;                // TB floats
    float*    accum    = lgits + TBTOK;
    float*    OWp      = accum + 2;                  // padded head vecs (1280 ea)
    float*    L1bp     = OWp + P_PAD;
    float*    L2bp     = L1bp + P_PAD;

    // bf16 weight arena offsets (elements); wq||wk contiguous for merged QK
    ushort_t* wqk_b = wtb + 0;         // 1024 x 640
    ushort_t* wv_b  = wtb + 655360;
    ushort_t* wo_b  = wtb + 1245184;
    ushort_t* w1_b  = wtb + 1507328;
    ushort_t* w2_b  = wtb + 1769472;
    ushort_t* l1_b  = wtb + 2031616;   // 1280 x 1152 (padded rows)
    ushort_t* l2_b  = wtb + 3506176;   // 1280 x 1280 (padded rows+cols)

    convert_weights<<<1984, 256, 0, stream>>>(Wq, Wk, Wv, Wo, W1, W2, wtb, accum);
    pad_weights<<<3041, 256, 0, stream>>>(L1W, L2W, L1b, L2b, OW,
                                          l1_b, l2_b, L1bp, L2bp, OWp);
    // embeddings + fused logits tail dot
    embed_kernel<<<TBTOK, 256, 0, stream>>>(ans, cans, labels, mask, qids, sids,
                                            smask, Eq, Es, Ea, El, pred_bf, value_bf,
                                            OW, Ob, lgits);
    // merged Q|K projection (Q pre-scaled by 1/8): 128x256 tiles, 128x4 grid
    gemmT<4,5,false><<<dim3(128, 4), 512, 0, stream>>>(
        pred_bf + 512, P_DIM, wqk_b, 640, bq, bk, qb, kb, 0, 640, nullptr, nullptr);
    // V^T: 128x128 tiles, 128x4 grid, permuted A-row consumption
    gemmT<2,4,false><<<dim3(128, 4), 512, 0, stream>>>(
        value_bf, P_DIM, wv_b, P_DIM, bv, nullptr, vtb, nullptr, 0, P_DIM, nullptr, nullptr);
    // attention (MFMA flash, async LDS staging)
    attn_mfma<<<dim3(B_SZ * NHEAD, 8), 256, 0, stream>>>(
        qb, kb, vtb, mask, gammas, attnc_bf);
    // output projection -> x1_bf
    gemmT<2,1,false><<<dim3(128, 4), 512, 0, stream>>>(
        attnc_bf, H_DIM, wo_b, H_DIM, bo, nullptr, x1_bf, nullptr, H_DIM, H_DIM, nullptr, nullptr);
    ln1_kernel<<<TBTOK/4, 256, 0, stream>>>(x1_bf, ln1_g, ln1_b, out1_bf);
    // FFN
    gemmT<2,1,true><<<dim3(128, 4), 512, 0, stream>>>(
        out1_bf, H_DIM, w1_b, H_DIM, b1, nullptr, f1_bf, nullptr, H_DIM, H_DIM, nullptr, nullptr);
    gemmT<2,1,false><<<dim3(128, 4), 512, 0, stream>>>(
        f1_bf, H_DIM, w2_b, H_DIM, b2, nullptr, f2_bf, nullptr, H_DIM, H_DIM, nullptr, nullptr);
    // LN2 + bf16 residual + fused head-dot into lgits
    ln2_kernel<<<TBTOK/4, 256, 0, stream>>>(f2_bf, ln2_g, ln2_b, out1_bf, pred_bf, OW, lgits);
    // L1 (relu) -> h1 [16384][1280]: 128x320 tiles, 128x4 grid
    gemmT<5,1,true><<<dim3(128, 4), 512, 0, stream>>>(
        pred_bf, P_DIM, l1_b, P_DIM, L1bp, nullptr, h1_bf, nullptr, P_PAD, P_DIM, nullptr, nullptr);
    // L2 (relu) + OW dot -> per-block partials (no atomics)
    gemmT<5,3,true><<<dim3(128, 4), 512, 0, stream>>>(
        h1_bf, P_PAD, l2_b, P_PAD, L2bp, nullptr, nullptr, nullptr, 0, P_PAD, OWp, l2part);
    // BCE + reduction (sums the 4 L2 partials per token)
    bce_kernel<<<TBTOK/256, 256, 0, stream>>>(lgits, l2part, labels, mask, accum);
    finalize_kernel<<<1, 1, 0, stream>>>(accum, out);
}

// Round 12
// 405.113 us; speedup vs baseline: 1.1439x; 1.1056x over previous
//
#include <hip/hip_runtime.h>
#include <math.h>

// Problem constants
#define T_LEN 512
#define B_SZ  32
#define NHEAD 8
#define DHEAD 64
#define H_DIM 512
#define TBTOK 16384          // T*B
#define P_DIM 1152
#define P_PAD 1280           // P padded for the 320-wide gemm

typedef unsigned short ushort_t;
typedef short short8 __attribute__((ext_vector_type(8)));
typedef float f32x4 __attribute__((ext_vector_type(4)));

__device__ __forceinline__ ushort_t f2bf(float f) {
    union { float f; unsigned int u; } v; v.f = f;
    unsigned int r = v.u + 0x7fffu + ((v.u >> 16) & 1u);
    return (ushort_t)(r >> 16);
}
__device__ __forceinline__ float bf2f(ushort_t h) {
    union { unsigned int u; float f; } v; v.u = ((unsigned int)h) << 16;
    return v.f;
}
__device__ __forceinline__ void gload_lds16(const void* g, void* l) {
    __builtin_amdgcn_global_load_lds(
        (const __attribute__((address_space(1))) void*)g,
        (__attribute__((address_space(3))) void*)l, 16, 0, 0);
}

// ---------------------------------------------------------------------------
// Weight fp32 -> bf16 packing (first 6 matrices, flat) + accum zero
// ---------------------------------------------------------------------------
__global__ __launch_bounds__(256) void convert_weights(
    const float* __restrict__ wq, const float* __restrict__ wk,
    const float* __restrict__ wv, const float* __restrict__ wo,
    const float* __restrict__ w1, const float* __restrict__ w2,
    ushort_t* __restrict__ dst, float* __restrict__ accum)
{
    if (blockIdx.x == 0 && threadIdx.x < 2) accum[threadIdx.x] = 0.f;
    const unsigned int offs[7] = {0u, 327680u, 655360u, 1245184u, 1507328u,
                                  1769472u, 2031616u};
    unsigned int c = (blockIdx.x * 256 + threadIdx.x) * 4;   // element offset
    const float* srcs[6] = {wq, wk, wv, wo, w1, w2};
    int s = 0;
#pragma unroll
    for (int i = 0; i < 5; i++) s += (c >= offs[i + 1]) ? 1 : 0;
    float4 v = *(const float4*)(srcs[s] + (c - offs[s]));
    ushort4 o;
    o.x = f2bf(v.x); o.y = f2bf(v.y); o.z = f2bf(v.z); o.w = f2bf(v.w);
    *(ushort4*)(dst + c) = o;
}

// ---------------------------------------------------------------------------
// L1W -> [1280][1152] bf16 (zero pad rows), L2W -> [1280][1280] bf16
// (zero pad rows+cols), plus padded L1b/L2b/OW float vectors (1280).
// ---------------------------------------------------------------------------
__global__ __launch_bounds__(256) void pad_weights(
    const float* __restrict__ l1, const float* __restrict__ l2,
    const float* __restrict__ L1b, const float* __restrict__ L2b,
    const float* __restrict__ OW,
    ushort_t* __restrict__ l1d, ushort_t* __restrict__ l2d,
    float* __restrict__ L1bp, float* __restrict__ L2bp, float* __restrict__ OWp)
{
    int blk = blockIdx.x;
    if (blk < 1440) {                       // l1: 1280*1152 = 1,474,560 elems
        int o4 = (blk * 256 + threadIdx.x) * 4;
        int row = o4 / 1152;
        int col = o4 - row * 1152;
        ushort4 o; o.x = 0; o.y = 0; o.z = 0; o.w = 0;
        if (row < 1152) {
            float4 v = *(const float4*)(l1 + (size_t)row * 1152 + col);
            o.x = f2bf(v.x); o.y = f2bf(v.y); o.z = f2bf(v.z); o.w = f2bf(v.w);
        }
        *(ushort4*)(l1d + o4) = o;
    } else if (blk < 3040) {                // l2: 1280*1280 = 1,638,400 elems
        int o4 = ((blk - 1440) * 256 + threadIdx.x) * 4;
        int row = o4 / 1280;
        int col = o4 - row * 1280;
        ushort4 o; o.x = 0; o.y = 0; o.z = 0; o.w = 0;
        if (row < 1152 && col < 1152) {     // 4-chunk never straddles 1152 (4|1152)
            float4 v = *(const float4*)(l2 + (size_t)row * 1152 + col);
            o.x = f2bf(v.x); o.y = f2bf(v.y); o.z = f2bf(v.z); o.w = f2bf(v.w);
        }
        *(ushort4*)(l2d + o4) = o;
    } else {
        for (int i = threadIdx.x; i < P_PAD; i += 256) {
            L1bp[i] = (i < P_DIM) ? L1b[i] : 0.f;
            L2bp[i] = (i < P_DIM) ? L2b[i] : 0.f;
            OWp[i]  = (i < P_DIM) ? OW[i]  : 0.f;
        }
    }
}

// ---------------------------------------------------------------------------
// Embedding / gather (bf16 outputs) + fused logits tail dot
// ---------------------------------------------------------------------------
__global__ __launch_bounds__(256) void embed_kernel(
    const int* __restrict__ ans, const int* __restrict__ cans,
    const int* __restrict__ labels, const float* __restrict__ mask,
    const int* __restrict__ qids, const int* __restrict__ sids,
    const float* __restrict__ smask,
    const float* __restrict__ Eq, const float* __restrict__ Es,
    const float* __restrict__ Ea, const float* __restrict__ El,
    ushort_t* __restrict__ pred_bf, ushort_t* __restrict__ value_bf,
    const float* __restrict__ OW, const float* __restrict__ Ob,
    float* __restrict__ lgits)
{
    __shared__ float red[4];
    int m = blockIdx.x;              // token = t*B + b
    int tid = threadIdx.x;           // 256
    float mval = mask[m];
    int qid = qids[m];
    int a   = ans[m] - 1;
    int ca  = cans[m] - 1;
    int lb  = labels[m];
    ushort_t* pr = pred_bf  + (size_t)m * P_DIM;
    ushort_t* vr = value_bf + (size_t)m * P_DIM;

    float part = 0.f;
    if (tid < 128) {
        ushort_t qv = f2bf(Eq[(size_t)qid * 128 + tid]);
        pr[512 + tid] = qv;
        vr[768 + tid] = qv;
        part = bf2f(qv) * OW[512 + tid];
    }
    int d = tid;                     // 0..255
    float s = 0.f;
#pragma unroll
    for (int j = 0; j < 8; j++) {
        int  sid = sids[m * 8 + j];
        float sm = smask[m * 8 + j];
        s += Es[(size_t)sid * 256 + d] * sm;
    }
    ushort_t sb = f2bf(s);
    pr[640 + d] = sb;
    vr[896 + d] = sb;
    ushort_t cab = f2bf(Ea[ca * 256 + d]);
    pr[896 + d] = cab;
    vr[512 + d] = cab;
    vr[256 + d] = f2bf(Ea[a * 256 + d] * mval);
    vr[0   + d] = f2bf(El[lb * 256 + d] * mval);

    part = fmaf(bf2f(sb),  OW[640 + d], part);
    part = fmaf(bf2f(cab), OW[896 + d], part);
#pragma unroll
    for (int off = 32; off >= 1; off >>= 1) part += __shfl_xor(part, off, 64);
    if ((tid & 63) == 0) red[tid >> 6] = part;
    __syncthreads();
    if (tid == 0) lgits[m] = red[0] + red[1] + red[2] + red[3] + Ob[0];
}

// ---------------------------------------------------------------------------
// TLP-overlapped MFMA GEMM (r21 = r9's empirically-fastest layout + the
// de-atomic MODE 3 epilogue).
// 128 x (64*JC) tile, BK=64, 512 thr = 8 waves (2M x 4N), per-wave C =
// 64 x (16*JC) (acc[4][JC]). Grid = 128 x 4 = 512 wgs = 2+ blocks/CU
// (m114 TLP). LDS single-buffered 64-elem rows (r9 layout): A[128x64]
// 16KB + B[BNx64]; staging requests are 128B/row (8 rows/instr) --
// r10's khalf-split layout halved request size to 64B and REGRESSED
// total 405.7 -> 463.4 with 3x HBM traffic on the L2 dispatch
// (mechanism unresolved; r9 layout is the measured-fastest, its ~4-way
// LDS read conflicts notwithstanding). Serial loop: stage -> vmcnt(0)
// -> barrier -> compute (2 khalves via cs roll) -> barrier.
// MODE 3 (r11): NO global atomics -- LDS reduce over wn waves, one
// contiguous 512B store per block into lg[by*TBTOK+m]; bce sums 4
// partials. (r10->r11: -15.5us total.)
// MODE 1: bias + optional relu, bf16 row-major store (ldc)
// MODE 4: JC=2, V^T scatter [bh][d][t]; A rows consumed (b,t)-permuted
// MODE 5: JC=4, merged Q|K scatter [bh][t][d]
// Epilogue stages alias SH (all waves past final barrier; wave-private).
// ---------------------------------------------------------------------------
template<int JC, int MODE, bool RELU>
__global__ __launch_bounds__(512, 4) void gemmT(
    const ushort_t* __restrict__ A, int lda,
    const ushort_t* __restrict__ W, int ldw,
    const float* __restrict__ bias, const float* __restrict__ bias2,
    ushort_t* __restrict__ Cb, ushort_t* __restrict__ Cb2, int ldc, int K,
    const float* __restrict__ OW, float* __restrict__ lg)
{
    constexpr int BN = JC * 64;
    __shared__ __align__(16) ushort_t SH[128 * 64 + BN * 64]; // 16 + 8*JC KB
    ushort_t* Bs = SH + 128 * 64;

    const int m0 = blockIdx.x * 128;
    const int n0 = blockIdx.y * BN;
    const int wave = threadIdx.x >> 6;
    const int lane = threadIdx.x & 63;
    const int wm = wave >> 2, wn = wave & 3;   // 2M x 4N waves
    const int fr   = lane & 15;
    const int quad = lane >> 4;

    // staging: instr covers 8 rows; lane -> row +(lane>>3), phys chunk
    // lane&7, source chunk ((lane&7) - roll) & 7, roll = ((row)>>1)&7 =
    // (wave*4 + (slr>>1)) & 7 (row-block offsets mult of 64 drop out).
    const int slr = lane >> 3;
    const int sc  = (((lane & 7) - ((wave * 4 + (slr >> 1)) & 7)) & 7) * 8;
    const ushort_t* Asrc;
    size_t aRS;   // A address stride per +1 staged row
    if (MODE == 4) {
        // token(r) = ((m0&511)+r)*32 + (m0>>9); affine in r (128 | m0)
        Asrc = A + (size_t)(((m0 & 511) + slr) * 32 + (m0 >> 9)) * lda + sc;
        aRS  = (size_t)32 * lda;
    } else {
        Asrc = A + (size_t)(m0 + slr) * lda + sc;
        aRS  = (size_t)lda;
    }
    const ushort_t* Wsrc = W + (size_t)(n0 + slr) * ldw + sc;
    const int NT = K >> 6;

    auto stA = [&](int t) {              // 16 instrs: 2 per wave
#pragma unroll
        for (int n = 0; n < 2; n++) {
            int rb = (wave + 8 * n) * 8;
            gload_lds16(Asrc + (size_t)rb * aRS + t * 64, &SH[rb * 64]);
        }
    };
    auto stB = [&](int t) {              // 8*JC instrs: JC per wave
#pragma unroll
        for (int n = 0; n < JC; n++) {
            int rb = (wave + 8 * n) * 8;
            gload_lds16(Wsrc + (size_t)rb * ldw + t * 64, &Bs[rb * 64]);
        }
    };

    f32x4 acc[4][JC] = {};

    for (int t = 0; t < NT; ++t) {
        stA(t); stB(t);
        asm volatile("s_waitcnt vmcnt(0)" ::: "memory");
        __builtin_amdgcn_s_barrier();
#pragma unroll
        for (int h = 0; h < 2; h++) {
            const int cs = ((h * 4 + quad + (fr >> 1)) & 7) * 8;
            short8 af[4], bf[JC];
#pragma unroll
            for (int i = 0; i < 4; i++)
                af[i] = *(const short8*)&SH[(wm * 64 + i * 16 + fr) * 64 + cs];
#pragma unroll
            for (int j = 0; j < JC; j++)
                bf[j] = *(const short8*)&Bs[(wn * (JC * 16) + j * 16 + fr) * 64 + cs];
#pragma unroll
            for (int i = 0; i < 4; i++)
#pragma unroll
                for (int j = 0; j < JC; j++)
                    acc[i][j] = __builtin_amdgcn_mfma_f32_16x16x32_bf16(
                        af[i], bf[j], acc[i][j], 0, 0, 0);
        }
        __builtin_amdgcn_s_barrier();    // all reads done before next stage
    }

    // C/D layout per frag: col = fr, row = quad*4 + reg.
    // acc[ii][j] -> row = m0 + wm*64 + ii*16 + quad*4 + r
    const int nbase = n0 + wn * (JC * 16);

    if (MODE == 3) {
        // de-atomic epilogue: per-row partial -> LDS wn-plane -> one
        // contiguous per-block store into lg[by*TBTOK + m0 + rl].
        float* shp = (float*)SH;               // [4 wn][128 rl] floats
#pragma unroll
        for (int ii = 0; ii < 4; ii++)
#pragma unroll
            for (int r = 0; r < 4; r++) {
                int rl = wm * 64 + ii * 16 + quad * 4 + r;
                float part = 0.f;
#pragma unroll
                for (int j = 0; j < JC; j++) {
                    int col = nbase + j * 16 + fr;
                    float v = fmaxf(acc[ii][j][r] + bias[col], 0.f);
                    part = fmaf(v, OW[col], part);
                }
                part += __shfl_xor(part, 1, 64);
                part += __shfl_xor(part, 2, 64);
                part += __shfl_xor(part, 4, 64);
                part += __shfl_xor(part, 8, 64);
                if (fr == 0) shp[wn * 128 + rl] = part;
            }
        __syncthreads();
        int tid = threadIdx.x;
        if (tid < 128) {
            float v = shp[tid] + shp[128 + tid] + shp[256 + tid] + shp[384 + tid];
            lg[(size_t)blockIdx.y * TBTOK + m0 + tid] = v;
        }
        return;
    }

    if (MODE == 5) {
        // JC=4: per-wave 64 rows x 64 cols = one head's d-range.
        bool side = (nbase >= 512);
        const float* bp = side ? bias2 : bias;
        const int boff  = nbase & 511;
        const float scl = side ? 1.f : 0.125f;
        ushort_t* base  = side ? Cb2 : Cb;
        const int h = (nbase >> 6) & 7;
        ushort_t* etw = SH + wave * (16 * 72);
#pragma unroll
        for (int ii = 0; ii < 4; ii++) {
#pragma unroll
            for (int r = 0; r < 4; r++)
#pragma unroll
                for (int j = 0; j < 4; j++) {
                    float v = (acc[ii][j][r] + bp[boff + j * 16 + fr]) * scl;
                    etw[(quad * 4 + r) * 72 + j * 16 + fr] = f2bf(v);
                }
            int rowb = m0 + wm * 64 + ii * 16;
#pragma unroll
            for (int u = lane; u < 128; u += 64) {
                int rr = u >> 3, cc = (u & 7) * 8;
                int row = rowb + rr;            // token m = t*32 + b
                int tq = row >> 5, b = row & 31;
                short8 val = *(const short8*)&etw[rr * 72 + cc];
                *(short8*)&base[(((size_t)(b * 8 + h)) << 15) + ((size_t)tq << 6) + cc] = val;
            }
        }
        return;
    }

    if (MODE == 4) {
        // JC=2: per-wave 64 rows(m=b*512+t, same b) x 32 cols(d).
        // Transposed stage per 32-t half: 32 d x 32 t, scatter to
        // vtb[bh][d][512].
        ushort_t* etw = SH + wave * (32 * 40);
        const int h = nbase >> 6;
        const int dbase = nbase & 63;
        const int mbase = m0 + wm * 64;
        const int b = mbase >> 9;
        size_t obase0 = (((size_t)(b * 8 + h)) << 15) + ((size_t)dbase << 9)
                        + (mbase & 511);
#pragma unroll
        for (int p = 0; p < 2; p++) {
#pragma unroll
            for (int iiL = 0; iiL < 2; iiL++) {
                int ii = p * 2 + iiL;
#pragma unroll
                for (int r = 0; r < 4; r++) {
                    int rl = iiL * 16 + quad * 4 + r;    // t-offset 0..31
#pragma unroll
                    for (int j = 0; j < 2; j++) {
                        int cl = j * 16 + fr;            // d-offset 0..31
                        float v = acc[ii][j][r] + bias[nbase + cl];
                        etw[cl * 40 + rl] = f2bf(v);
                    }
                }
            }
            size_t obase = obase0 + p * 32;
#pragma unroll
            for (int u = lane; u < 128; u += 64) {
                int dr = u >> 2, cc = (u & 3) * 8;
                short8 val = *(const short8*)&etw[dr * 40 + cc];
                *(short8*)&Cb[obase + ((size_t)dr << 9) + cc] = val;
            }
        }
        return;
    }

    // MODE 1: per-ii stage 16 rows x JC*16 cols in wave-private LDS slice
    // (aliased onto SH), then coalesced short8 stores.
    {
        constexpr int STR = JC * 16 + 8;
        constexpr int CPR = 2 * JC;            // short8 chunks per row
        ushort_t* etw = SH + wave * (16 * STR);
#pragma unroll
        for (int ii = 0; ii < 4; ii++) {
#pragma unroll
            for (int r = 0; r < 4; r++)
#pragma unroll
                for (int j = 0; j < JC; j++) {
                    float v = acc[ii][j][r] + bias[nbase + j * 16 + fr];
                    if (RELU) v = fmaxf(v, 0.f);
                    etw[(quad * 4 + r) * STR + j * 16 + fr] = f2bf(v);
                }
            int rowb = m0 + wm * 64 + ii * 16;
#pragma unroll
            for (int u = lane; u < 16 * CPR; u += 64) {
                int rr = u / CPR;
                int cc = u - rr * CPR;
                short8 val = *(const short8*)&etw[rr * STR + cc * 8];
                *(short8*)&Cb[(size_t)(rowb + rr) * ldc + nbase + cc * 8] = val;
            }
        }
    }
}

// ---------------------------------------------------------------------------
// MFMA flash attention, no-rescale softmax, cooperative async K/V LDS staging
// ---------------------------------------------------------------------------
__global__ __launch_bounds__(256) void attn_mfma(
    const ushort_t* __restrict__ qb, const ushort_t* __restrict__ kb,
    const ushort_t* __restrict__ vtb, const float* __restrict__ mask,
    const float* __restrict__ gammas, ushort_t* __restrict__ attnc)
{
    __shared__ __align__(16) ushort_t kbuf[2][64 * 64];  // 16 KB
    __shared__ __align__(16) ushort_t vbuf[2][64 * 64];  // 16 KB
    __shared__ __align__(16) ushort_t ps[4][16][72];     // P / O stage, per wave
    __shared__ float decayF[512];
    __shared__ float mneg[512];

    const int bh  = blockIdx.x;          // b*8 + h
    const int b   = bh >> 3;
    const int h   = bh & 7;
    const int qt0 = (7 - blockIdx.y) * 64;   // heavy tiles first
    const int tid  = threadIdx.x;
    const int wave = tid >> 6;
    const int lane = tid & 63;
    const int fr   = lane & 15;
    const int quad = lane >> 4;

    {   // LUTs: decay' = clip(exp(-sp*sqrt(d)),1e-5,..)*log2e ; mneg = 0/-1e32
        float g  = gammas[h];
        float sp = (g > 20.f) ? g : log1pf(expf(g));
        for (int i = tid; i < 512; i += 256) {
            decayF[i] = fmaxf(exp2f(-sp * 1.44269504f * sqrtf((float)i)), 1e-5f)
                        * 1.44269504f;
            mneg[i]   = (mask[(size_t)i * B_SZ + b] == 0.f) ? -1e32f : 0.f;
        }
    }

    const int qr0 = qt0 + wave * 16;
    const ushort_t* qbase = qb  + ((size_t)bh << 15);   // [t][64]
    const ushort_t* kbase = kb  + ((size_t)bh << 15);
    const ushort_t* vbase = vtb + ((size_t)bh << 15);   // [d][512]

    short8 af0 = *(const short8*)(qbase + (size_t)(qr0 + fr) * 64 + quad * 8);
    short8 af1 = *(const short8*)(qbase + (size_t)(qr0 + fr) * 64 + 32 + quad * 8);
    const short8 ones = {0x3F80, 0x3F80, 0x3F80, 0x3F80,
                         0x3F80, 0x3F80, 0x3F80, 0x3F80};

    const int rl0 = wave * 16 + (lane >> 3);
    const int rl1 = rl0 + 8;
    const int sc0 = (((lane & 7) - rl0) & 7) * 8;   // ushort offset
    const int sc1 = (((lane & 7) - rl1) & 7) * 8;

    auto stage = [&](int kt, int bufi) {
        gload_lds16(kbase + (size_t)(kt + rl0) * 64 + sc0, &kbuf[bufi][(wave * 16) * 64]);
        gload_lds16(kbase + (size_t)(kt + rl1) * 64 + sc1, &kbuf[bufi][(wave * 16 + 8) * 64]);
        gload_lds16(vbase + (size_t)rl0 * T_LEN + kt + sc0, &vbuf[bufi][(wave * 16) * 64]);
        gload_lds16(vbase + (size_t)rl1 * T_LEN + kt + sc1, &vbuf[bufi][(wave * 16 + 8) * 64]);
    };
    auto frag = [&](const ushort_t* buf, int row, int lchunk) -> short8 {
        return *(const short8*)&buf[row * 64 + ((lchunk + row) & 7) * 8];
    };

    stage(0, 0);

    f32x4 o[4] = {};                    // O[q=quad*4+r][d=j2*16+fr]
    f32x4 lacc = {};                    // row sums, same layout rows
    int bufi = 0;

    for (int kt0 = 0; kt0 <= qt0; kt0 += 64) {
        __syncthreads();                // drains staged loads; buffer handoff
        if (kt0 < qt0) stage(kt0 + 64, bufi ^ 1);   // prefetch during compute
        const bool diag = (kt0 == qt0);
        const ushort_t* kb_ = kbuf[bufi];
        const ushort_t* vb_ = vbuf[bufi];

        // ---- S = Q K^T (16 x 64) ----
        f32x4 sacc[4] = {};
#pragma unroll
        for (int j = 0; j < 4; j++) {
            int row = j * 16 + fr;
            short8 k0 = frag(kb_, row, quad);
            short8 k1 = frag(kb_, row, quad + 4);
            sacc[j] = __builtin_amdgcn_mfma_f32_16x16x32_bf16(af0, k0, sacc[j], 0, 0, 0);
            sacc[j] = __builtin_amdgcn_mfma_f32_16x16x32_bf16(af1, k1, sacc[j], 0, 0, 0);
        }

        // ---- softmax (no rescale): p = exp2(fma(s, decay', mneg)) ----
#pragma unroll
        for (int j = 0; j < 4; j++) {
            int kg = kt0 + j * 16 + fr;
            float mn = mneg[kg];
            int qgb = qr0 + quad * 4;
            if (!diag) {
                int base = qgb - kg;
#pragma unroll
                for (int r = 0; r < 4; r++) {
                    float t = fmaf(sacc[j][r], decayF[base + r], mn);
                    union { float f; unsigned u; } cv; cv.f = exp2f(t);
                    ps[wave][quad * 4 + r][j * 16 + fr] = (ushort_t)(cv.u >> 16);
                }
            } else {
#pragma unroll
                for (int r = 0; r < 4; r++) {
                    int didx = qgb + r - kg;
                    float dec = decayF[didx > 0 ? didx : 0];
                    float t = fmaf(sacc[j][r], dec, mn);
                    if (didx <= 0) t = -1e32f;      // causal (kg >= qg)
                    union { float f; unsigned u; } cv; cv.f = exp2f(t);
                    ps[wave][quad * 4 + r][j * 16 + fr] = (ushort_t)(cv.u >> 16);
                }
            }
        }
        short8 pf0 = *(const short8*)&ps[wave][fr][quad * 8];
        short8 pf1 = *(const short8*)&ps[wave][fr][32 + quad * 8];
        lacc = __builtin_amdgcn_mfma_f32_16x16x32_bf16(pf0, ones, lacc, 0, 0, 0);
        lacc = __builtin_amdgcn_mfma_f32_16x16x32_bf16(pf1, ones, lacc, 0, 0, 0);
#pragma unroll
        for (int j2 = 0; j2 < 4; j2++) {
            int row = j2 * 16 + fr;
            short8 v0 = frag(vb_, row, quad);
            short8 v1 = frag(vb_, row, quad + 4);
            o[j2] = __builtin_amdgcn_mfma_f32_16x16x32_bf16(pf0, v0, o[j2], 0, 0, 0);
            o[j2] = __builtin_amdgcn_mfma_f32_16x16x32_bf16(pf1, v1, o[j2], 0, 0, 0);
        }
        bufi ^= 1;
    }

    // epilogue: divide by l, zero row q==0, stage + coalesced store
#pragma unroll
    for (int r = 0; r < 4; r++) {
        int qg = qr0 + quad * 4 + r;
        float linv = (qg == 0) ? 0.f : 1.f / lacc[r];
#pragma unroll
        for (int j2 = 0; j2 < 4; j2++)
            ps[wave][quad * 4 + r][j2 * 16 + fr] = f2bf(o[j2][r] * linv);
    }
    const int sub8 = (lane & 7) * 8;
    const int grp  = lane >> 3;
#pragma unroll
    for (int half = 0; half < 2; half++) {
        int rowl = half * 8 + grp;                   // 0..15
        short8 val = *(const short8*)&ps[wave][rowl][sub8];
        int qg = qr0 + rowl;
        *(short8*)&attnc[((size_t)qg * B_SZ + b) * H_DIM + h * DHEAD + sub8] = val;
    }
}

// ---------------------------------------------------------------------------
// LN1: reads bf16 X, writes bf16 out1 only (residual kept in bf16)
// ---------------------------------------------------------------------------
__global__ __launch_bounds__(256) void ln1_kernel(
    const ushort_t* __restrict__ X, const float* __restrict__ g,
    const float* __restrict__ bta, ushort_t* __restrict__ Yb)
{
    int m    = blockIdx.x * 4 + (threadIdx.x >> 6);
    int lane = threadIdx.x & 63;
    int c0   = lane * 8;
    const ushort_t* xr = X + (size_t)m * H_DIM + c0;
    float x[8];
    float s = 0.f, ss = 0.f;
    short8 xv = *(const short8*)xr;
#pragma unroll
    for (int i = 0; i < 8; i++) {
        x[i] = bf2f((ushort_t)xv[i]);
        s += x[i]; ss += x[i] * x[i];
    }
#pragma unroll
    for (int off = 32; off >= 1; off >>= 1) {
        s  += __shfl_xor(s,  off, 64);
        ss += __shfl_xor(ss, off, 64);
    }
    float mu  = s * (1.f / 512.f);
    float var = ss * (1.f / 512.f) - mu * mu;
    float rs  = rsqrtf(var + 1e-5f);
    ushort_t yb[8];
#pragma unroll
    for (int i = 0; i < 8; i++)
        yb[i] = f2bf((x[i] - mu) * rs * g[c0 + i] + bta[c0 + i]);
    *(short8*)(Yb + (size_t)m * H_DIM + c0) = *(short8*)&yb[0];
}

// ---------------------------------------------------------------------------
// LN2 + residual (bf16) + fused OW-dot
// ---------------------------------------------------------------------------
__global__ __launch_bounds__(256) void ln2_kernel(
    const ushort_t* __restrict__ X, const float* __restrict__ g,
    const float* __restrict__ bta, const ushort_t* __restrict__ res,
    ushort_t* __restrict__ pred_bf, const float* __restrict__ OW,
    float* __restrict__ lg)
{
    int m    = blockIdx.x * 4 + (threadIdx.x >> 6);
    int lane = threadIdx.x & 63;
    int c0   = lane * 8;
    const ushort_t* xr = X + (size_t)m * H_DIM + c0;
    float x[8];
    float s = 0.f, ss = 0.f;
    short8 xv = *(const short8*)xr;
#pragma unroll
    for (int i = 0; i < 8; i++) {
        x[i] = bf2f((ushort_t)xv[i]);
        s += x[i]; ss += x[i] * x[i];
    }
#pragma unroll
    for (int off = 32; off >= 1; off >>= 1) {
        s  += __shfl_xor(s,  off, 64);
        ss += __shfl_xor(ss, off, 64);
    }
    float mu  = s * (1.f / 512.f);
    float var = ss * (1.f / 512.f) - mu * mu;
    float rs  = rsqrtf(var + 1e-5f);
    short8 rv = *(const short8*)(res + (size_t)m * H_DIM + c0);
    ushort_t yb[8];
    float part = 0.f;
#pragma unroll
    for (int i = 0; i < 8; i++) {
        float v = (x[i] - mu) * rs * g[c0 + i] + bta[c0 + i] + bf2f((ushort_t)rv[i]);
        yb[i] = f2bf(v);
        part = fmaf(v, OW[c0 + i], part);
    }
    *(short8*)(pred_bf + (size_t)m * P_DIM + c0) = *(short8*)&yb[0];
#pragma unroll
    for (int off = 32; off >= 1; off >>= 1) part += __shfl_xor(part, off, 64);
    if (lane == 0) lg[m] += part;
}

// ---------------------------------------------------------------------------
// BCE: logit = lg[m] + sum of 4 per-by L2 partials (de-atomic path)
// ---------------------------------------------------------------------------
__global__ __launch_bounds__(256) void bce_kernel(
    const float* __restrict__ lg, const float* __restrict__ p4,
    const int* __restrict__ labels, const float* __restrict__ mask,
    float* __restrict__ accum)
{
    int m    = blockIdx.x * 256 + threadIdx.x;
    int lane = threadIdx.x & 63;
    float l  = lg[m] + p4[m] + p4[TBTOK + m] + p4[2 * TBTOK + m]
             + p4[3 * TBTOK + m];
    float y  = (float)labels[m];
    float mv = mask[m];
    float a  = (fmaxf(l, 0.f) - l * y + log1pf(expf(-fabsf(l)))) * mv;
#pragma unroll
    for (int off = 32; off >= 1; off >>= 1) {
        a  += __shfl_xor(a,  off, 64);
        mv += __shfl_xor(mv, off, 64);
    }
    if (lane == 0) {
        atomicAdd(accum,     a);
        atomicAdd(accum + 1, mv);
    }
}

__global__ void finalize_kernel(const float* __restrict__ accum, float* __restrict__ out)
{
    out[0] = accum[0] / accum[1];
}

// ---------------------------------------------------------------------------
extern "C" void kernel_launch(void* const* d_in, const int* in_sizes, int n_in,
                              void* d_out, int out_size, void* d_ws, size_t ws_size,
                              hipStream_t stream)
{
    (void)in_sizes; (void)n_in; (void)out_size;
    const int*   ans    = (const int*)  d_in[0];
    const int*   cans   = (const int*)  d_in[1];
    const int*   labels = (const int*)  d_in[2];
    const float* mask   = (const float*)d_in[3];
    const int*   qids   = (const int*)  d_in[4];
    const int*   sids   = (const int*)  d_in[5];
    const float* smask  = (const float*)d_in[6];
    const float* Eq     = (const float*)d_in[7];
    const float* Es     = (const float*)d_in[8];
    const float* Ea     = (const float*)d_in[9];
    const float* El     = (const float*)d_in[10];
    const float* Wq     = (const float*)d_in[11];
    const float* bq     = (const float*)d_in[12];
    const float* Wk     = (const float*)d_in[13];
    const float* bk     = (const float*)d_in[14];
    const float* Wv     = (const float*)d_in[15];
    const float* bv     = (const float*)d_in[16];
    const float* Wo     = (const float*)d_in[17];
    const float* bo     = (const float*)d_in[18];
    const float* ln1_g  = (const float*)d_in[19];
    const float* ln1_b  = (const float*)d_in[20];
    const float* W1     = (const float*)d_in[21];
    const float* b1     = (const float*)d_in[22];
    const float* W2     = (const float*)d_in[23];
    const float* b2     = (const float*)d_in[24];
    const float* ln2_g  = (const float*)d_in[25];
    const float* ln2_b  = (const float*)d_in[26];
    const float* gammas = (const float*)d_in[27];
    const float* L1W    = (const float*)d_in[28];
    const float* L1b    = (const float*)d_in[29];
    const float* L2W    = (const float*)d_in[30];
    const float* L2b    = (const float*)d_in[31];
    const float* OW     = (const float*)d_in[32];
    const float* Ob     = (const float*)d_in[33];
    float* out = (float*)d_out;

    // Arena in units U = TB*64 floats (4 MiB). Peak ~176 MB.
    const size_t U = (size_t)TBTOK * 64;
    if (ws_size < 42 * U * sizeof(float)) return;
    float* ws = (float*)d_ws;
    ushort_t* wtb      = (ushort_t*)(ws);            // [0,3)  weights bf16 (perm)
    ushort_t* pred_bf  = (ushort_t*)(ws + 3 * U);    // [3,12) perm
    ushort_t* value_bf = (ushort_t*)(ws + 12 * U);   // [12,21) until V-gemm
    ushort_t* qb       = (ushort_t*)(ws + 21 * U);   // [21,25) until attn
    ushort_t* kb       = (ushort_t*)(ws + 25 * U);   // [25,29) until attn
    ushort_t* vtb      = (ushort_t*)(ws + 29 * U);   // [29,33) until attn
    ushort_t* attnc_bf = (ushort_t*)(ws + 33 * U);   // [33,37) until Wo
    ushort_t* x1_bf    = (ushort_t*)(ws + 12 * U);   // [12,16) Wo-out / LN1-in
    ushort_t* out1_bf  = (ushort_t*)(ws + 24 * U);   // [24,28) LN1..LN2 (bf16)
    ushort_t* f1_bf    = (ushort_t*)(ws + 28 * U);   // [28,32) W1-out
    ushort_t* f2_bf    = (ushort_t*)(ws + 32 * U);   // [32,36) W2-out / LN2-in
    ushort_t* h1_bf    = (ushort_t*)(ws + 12 * U);   // [12,22) L1-out (16384x1280)
    float*    l2part   = ws + 40 * U;                // [40,41) 4 x TB partials
    float*    lgits    = ws + 41 * U;                // TB floats
    float*    accum    = lgits + TBTOK;
    float*    OWp      = accum + 2;                  // padded head vecs (1280 ea)
    float*    L1bp     = OWp + P_PAD;
    float*    L2bp     = L1bp + P_PAD;

    // bf16 weight arena offsets (elements); wq||wk contiguous for merged QK
    ushort_t* wqk_b = wtb + 0;         // 1024 x 640
    ushort_t* wv_b  = wtb + 655360;
    ushort_t* wo_b  = wtb + 1245184;
    ushort_t* w1_b  = wtb + 1507328;
    ushort_t* w2_b  = wtb + 1769472;
    ushort_t* l1_b  = wtb + 2031616;   // 1280 x 1152 (padded rows)
    ushort_t* l2_b  = wtb + 3506176;   // 1280 x 1280 (padded rows+cols)

    convert_weights<<<1984, 256, 0, stream>>>(Wq, Wk, Wv, Wo, W1, W2, wtb, accum);
    pad_weights<<<3041, 256, 0, stream>>>(L1W, L2W, L1b, L2b, OW,
                                          l1_b, l2_b, L1bp, L2bp, OWp);
    // embeddings + fused logits tail dot
    embed_kernel<<<TBTOK, 256, 0, stream>>>(ans, cans, labels, mask, qids, sids,
                                            smask, Eq, Es, Ea, El, pred_bf, value_bf,
                                            OW, Ob, lgits);
    // merged Q|K projection (Q pre-scaled by 1/8): 128x256 tiles, 128x4 grid
    gemmT<4,5,false><<<dim3(128, 4), 512, 0, stream>>>(
        pred_bf + 512, P_DIM, wqk_b, 640, bq, bk, qb, kb, 0, 640, nullptr, nullptr);
    // V^T: 128x128 tiles, 128x4 grid, permuted A-row consumption
    gemmT<2,4,false><<<dim3(128, 4), 512, 0, stream>>>(
        value_bf, P_DIM, wv_b, P_DIM, bv, nullptr, vtb, nullptr, 0, P_DIM, nullptr, nullptr);
    // attention (MFMA flash, async LDS staging)
    attn_mfma<<<dim3(B_SZ * NHEAD, 8), 256, 0, stream>>>(
        qb, kb, vtb, mask, gammas, attnc_bf);
    // output projection -> x1_bf
    gemmT<2,1,false><<<dim3(128, 4), 512, 0, stream>>>(
        attnc_bf, H_DIM, wo_b, H_DIM, bo, nullptr, x1_bf, nullptr, H_DIM, H_DIM, nullptr, nullptr);
    ln1_kernel<<<TBTOK/4, 256, 0, stream>>>(x1_bf, ln1_g, ln1_b, out1_bf);
    // FFN
    gemmT<2,1,true><<<dim3(128, 4), 512, 0, stream>>>(
        out1_bf, H_DIM, w1_b, H_DIM, b1, nullptr, f1_bf, nullptr, H_DIM, H_DIM, nullptr, nullptr);
    gemmT<2,1,false><<<dim3(128, 4), 512, 0, stream>>>(
        f1_bf, H_DIM, w2_b, H_DIM, b2, nullptr, f2_bf, nullptr, H_DIM, H_DIM, nullptr, nullptr);
    // LN2 + bf16 residual + fused head-dot into lgits
    ln2_kernel<<<TBTOK/4, 256, 0, stream>>>(f2_bf, ln2_g, ln2_b, out1_bf, pred_bf, OW, lgits);
    // L1 (relu) -> h1 [16384][1280]: 128x320 tiles, 128x4 grid
    gemmT<5,1,true><<<dim3(128, 4), 512, 0, stream>>>(
        pred_bf, P_DIM, l1_b, P_DIM, L1bp, nullptr, h1_bf, nullptr, P_PAD, P_DIM, nullptr, nullptr);
    // L2 (relu) + OW dot -> per-block partials (no atomics)
    gemmT<5,3,true><<<dim3(128, 4), 512, 0, stream>>>(
        h1_bf, P_PAD, l2_b, P_PAD, L2bp, nullptr, nullptr, nullptr, 0, P_PAD, OWp, l2part);
    // BCE + reduction (sums the 4 L2 partials per token)
    bce_kernel<<<TBTOK/256, 256, 0, stream>>>(lgits, l2part, labels, mask, accum);
    finalize_kernel<<<1, 1, 0, stream>>>(accum, out);
}